// Round 2
// baseline (691.906 us; speedup 1.0000x reference)
//
#include <hip/hip_runtime.h>
#include <hip/hip_bf16.h>

// DRSA temporal block, fp32 reference-faithful implementation.
// Dims: B=2, P=8, hp=8, W=24, C=256, NH=8, dk=32, kv=4, H=64.
// 3072 total positions, everything kept in [pos=3072][C=256] row-major.

#define NPOS 3072          // B*H*W = B*P*hp*W
#define CD   256
#define NE   (NPOS*CD)     // 786432 floats per tensor

// ---------------------------------------------------------------- GEMM triple
// O = A @ W + bias for up to 3 independent (A,W,bias,O) sets selected by blockIdx.y.
// Tile: 32 rows x 256 cols per block, 256 threads, A tile staged in LDS.
__global__ __launch_bounds__(256) void gemm_k3(
    const float* __restrict__ A0, const float* __restrict__ A1, const float* __restrict__ A2,
    const float* __restrict__ W0, const float* __restrict__ W1, const float* __restrict__ W2,
    const float* __restrict__ B0, const float* __restrict__ B1, const float* __restrict__ B2,
    float* __restrict__ O0, float* __restrict__ O1, float* __restrict__ O2)
{
    __shared__ float As[32*256];
    int which = blockIdx.y;
    const float* A  = which==0 ? A0 : (which==1 ? A1 : A2);
    const float* Wm = which==0 ? W0 : (which==1 ? W1 : W2);
    const float* Bi = which==0 ? B0 : (which==1 ? B1 : B2);
    float*       O  = which==0 ? O0 : (which==1 ? O1 : O2);
    int tid = threadIdx.x;
    int m0 = blockIdx.x * 32;
    #pragma unroll
    for (int j = 0; j < 32; ++j)
        As[j*256 + tid] = A[(size_t)(m0 + j)*256 + tid];
    __syncthreads();
    int cq = (tid & 63) * 4;   // 4 output cols
    int rg = (tid >> 6) * 8;   // 8 rows
    float4 acc[8];
    #pragma unroll
    for (int r = 0; r < 8; ++r) acc[r] = make_float4(0.f,0.f,0.f,0.f);
    for (int k = 0; k < 256; k += 4) {
        float4 b0 = *(const float4*)(Wm + (size_t)(k+0)*256 + cq);
        float4 b1 = *(const float4*)(Wm + (size_t)(k+1)*256 + cq);
        float4 b2 = *(const float4*)(Wm + (size_t)(k+2)*256 + cq);
        float4 b3 = *(const float4*)(Wm + (size_t)(k+3)*256 + cq);
        #pragma unroll
        for (int r = 0; r < 8; ++r) {
            float4 a = *(const float4*)(As + (rg + r)*256 + k);  // wave-uniform b128 (broadcast)
            acc[r].x += a.x*b0.x + a.y*b1.x + a.z*b2.x + a.w*b3.x;
            acc[r].y += a.x*b0.y + a.y*b1.y + a.z*b2.y + a.w*b3.y;
            acc[r].z += a.x*b0.z + a.y*b1.z + a.z*b2.z + a.w*b3.z;
            acc[r].w += a.x*b0.w + a.y*b1.w + a.z*b2.w + a.w*b3.w;
        }
    }
    float4 bb = *(const float4*)(Bi + cq);
    #pragma unroll
    for (int r = 0; r < 8; ++r) {
        float4 o = acc[r];
        o.x += bb.x; o.y += bb.y; o.z += bb.z; o.w += bb.w;
        *(float4*)(O + (size_t)(m0 + rg + r)*256 + cq) = o;
    }
}

// ---------------------------------------------------------------- k_p + v_p
__global__ __launch_bounds__(256) void addkv(
    const float* __restrict__ a, const float* __restrict__ b, float* __restrict__ o)
{
    int i = blockIdx.x*256 + threadIdx.x;   // one float4 per thread, grid covers NE/4
    float4 av = *(const float4*)(a + (size_t)i*4);
    float4 bv = *(const float4*)(b + (size_t)i*4);
    float4 ov; ov.x = av.x+bv.x; ov.y = av.y+bv.y; ov.z = av.z+bv.z; ov.w = av.w+bv.w;
    *(float4*)(o + (size_t)i*4) = ov;
}

// ---------------------------------------------------------------- block descriptors
__global__ __launch_bounds__(256) void locmean(
    const float* __restrict__ qp, const float* __restrict__ kp,
    float* __restrict__ qloc, float* __restrict__ kloc)
{
    int bp = blockIdx.x;          // 0..15
    int c  = threadIdx.x;
    const float* src = blockIdx.y ? kp : qp;
    float*       dst = blockIdx.y ? kloc : qloc;
    float s = 0.f;
    for (int i = 0; i < 192; ++i)
        s += src[((size_t)(bp*192 + i))*256 + c];
    dst[bp*256 + c] = s * (1.0f/192.0f);
}

// ---------------------------------------------------------------- routing top-k
// jax.lax.top_k: descending, ties -> earlier index. Strict-> argmax sweep matches.
__global__ void topk_kern(const float* __restrict__ qloc, const float* __restrict__ kloc,
                          int* __restrict__ Rix)
{
    __shared__ float S[64];
    int b = blockIdx.x, t = threadIdx.x;
    int p = t >> 3, qq = t & 7;
    float s = 0.f;
    for (int c = 0; c < 256; ++c)
        s += qloc[(b*8+p)*256 + c] * kloc[(b*8+qq)*256 + c];
    S[t] = s;
    __syncthreads();
    if (t < 8) {
        float vals[8];
        #pragma unroll
        for (int j = 0; j < 8; ++j) vals[j] = S[t*8 + j];
        for (int j = 0; j < 4; ++j) {
            int best = 0; float bv = vals[0];
            #pragma unroll
            for (int i = 1; i < 8; ++i) if (vals[i] > bv) { bv = vals[i]; best = i; }
            Rix[(b*8 + t)*4 + j] = best;
            vals[best] = -1e30f;
        }
    }
}

// ---------------------------------------------------------------- attention partials
// grid (128 = bp*8+h, 4 = kv block), 192 threads = one query each.
// Online softmax over this kv-block's 192 keys; partial (m, l, acc[32]) to ws.
__global__ __launch_bounds__(192) void attn_partial(
    const float* __restrict__ qa, const float* __restrict__ ka, const float* __restrict__ va,
    const int* __restrict__ Rix, float* __restrict__ pml, float* __restrict__ pacc)
{
    __shared__ float Ks[64*32];
    __shared__ float Vs[64*32];
    int bph = blockIdx.x;              // bp*8 + h
    int kvb = blockIdx.y;              // 0..3
    int bp = bph >> 3, h = bph & 7;
    int b  = bp >> 3;
    int q  = threadIdx.x;              // 0..191
    int r  = Rix[bp*4 + kvb];          // routed block within P
    const float* Qrow  = qa + ((size_t)(bp*192 + q))*256 + h*32;
    const float* Kbase = ka + ((size_t)((b*8 + r)*192))*256 + h*32;
    const float* Vbase = va + ((size_t)((b*8 + r)*192))*256 + h*32;
    float4 qv[8];
    #pragma unroll
    for (int i = 0; i < 8; ++i) qv[i] = *(const float4*)(Qrow + i*4);
    float4 acc[8];
    #pragma unroll
    for (int i = 0; i < 8; ++i) acc[i] = make_float4(0.f,0.f,0.f,0.f);
    float m = -1e30f, l = 0.f;
    for (int c0 = 0; c0 < 192; c0 += 64) {
        __syncthreads();
        for (int idx = threadIdx.x; idx < 1024; idx += 192) {  // 512 float4 K + 512 float4 V
            int half = idx >> 9;
            int j = idx & 511;
            int key = j >> 3, d4 = (j & 7)*4;
            const float* src = (half ? Vbase : Kbase) + (size_t)(c0 + key)*256 + d4;
            float4 v = *(const float4*)src;
            float* dst = (half ? Vs : Ks) + key*32 + d4;
            *(float4*)dst = v;
        }
        __syncthreads();
        for (int key = 0; key < 64; ++key) {
            const float4* Kr = (const float4*)(Ks + key*32);
            float s = 0.f;
            #pragma unroll
            for (int i = 0; i < 8; ++i) {
                float4 kf = Kr[i];
                s += qv[i].x*kf.x + qv[i].y*kf.y + qv[i].z*kf.z + qv[i].w*kf.w;
            }
            s *= 0.17677669529663687f;   // 1/sqrt(32)
            if (s > m) {
                float corr = __expf(m - s);
                l *= corr;
                #pragma unroll
                for (int i = 0; i < 8; ++i) {
                    acc[i].x *= corr; acc[i].y *= corr; acc[i].z *= corr; acc[i].w *= corr;
                }
                m = s;
            }
            float e = __expf(s - m);
            l += e;
            const float4* Vr = (const float4*)(Vs + key*32);
            #pragma unroll
            for (int i = 0; i < 8; ++i) {
                float4 vf = Vr[i];
                acc[i].x += e*vf.x; acc[i].y += e*vf.y; acc[i].z += e*vf.z; acc[i].w += e*vf.w;
            }
        }
    }
    size_t pidx = ((size_t)(bph*4 + kvb))*192 + q;
    pml[pidx*2 + 0] = m;
    pml[pidx*2 + 1] = l;
    #pragma unroll
    for (int i = 0; i < 8; ++i)
        *(float4*)(pacc + pidx*32 + i*4) = acc[i];
}

// ---------------------------------------------------------------- merge partials -> ctx
__global__ __launch_bounds__(256) void attn_merge(
    const float* __restrict__ pml, const float* __restrict__ pacc, float* __restrict__ ctx)
{
    int idx = blockIdx.x*256 + threadIdx.x;   // 0..786431
    int d  = idx & 31;
    int gq = idx >> 5;                        // 0..24575
    int bph = gq / 192;
    int q = gq - bph*192;
    int bp = bph >> 3, h = bph & 7;
    float mk[4], lk[4];
    float M = -1e30f;
    #pragma unroll
    for (int k = 0; k < 4; ++k) {
        size_t p = ((size_t)(bph*4 + k))*192 + q;
        mk[k] = pml[p*2]; lk[k] = pml[p*2 + 1];
        M = fmaxf(M, mk[k]);
    }
    float wsum = 0.f, cv = 0.f;
    #pragma unroll
    for (int k = 0; k < 4; ++k) {
        float w = __expf(mk[k] - M);
        wsum += lk[k]*w;
        cv += w * pacc[(((size_t)(bph*4 + k))*192 + q)*32 + d];
    }
    ctx[((size_t)(bp*192 + q))*256 + h*32 + d] = cv / wsum;
}

// ---------------------------------------------------------------- residual + LayerNorm
// 4 positions per block, one wave per position (lane holds 4 channels).
__global__ __launch_bounds__(256) void ln_add(
    const float* __restrict__ A, const float* __restrict__ B1,
    const float* __restrict__ gamma, const float* __restrict__ beta,
    float* __restrict__ out)
{
    int pos  = blockIdx.x*4 + (threadIdx.x >> 6);
    int lane = threadIdx.x & 63;
    size_t base = (size_t)pos*256 + lane*4;
    float4 a = *(const float4*)(A + base);
    float4 b = *(const float4*)(B1 + base);
    float x0 = a.x + b.x, x1 = a.y + b.y, x2 = a.z + b.z, x3 = a.w + b.w;
    float s  = x0 + x1 + x2 + x3;
    float sq = x0*x0 + x1*x1 + x2*x2 + x3*x3;
    #pragma unroll
    for (int off = 32; off > 0; off >>= 1) {
        s  += __shfl_xor(s,  off);
        sq += __shfl_xor(sq, off);
    }
    float mean = s * (1.0f/256.0f);
    float var  = sq * (1.0f/256.0f) - mean*mean;
    float rstd = rsqrtf(var + 1e-5f);
    float4 gv = *(const float4*)(gamma + lane*4);
    float4 bv = *(const float4*)(beta  + lane*4);
    float4 o;
    o.x = (x0 - mean)*rstd*gv.x + bv.x;
    o.y = (x1 - mean)*rstd*gv.y + bv.y;
    o.z = (x2 - mean)*rstd*gv.z + bv.z;
    o.w = (x3 - mean)*rstd*gv.w + bv.w;
    *(float4*)(out + base) = o;
}

// ---------------------------------------------------------------- 5x5 SAME conv
// grid (B*H = 128 image rows, 2 co-halves), 256 threads. One haloed input row
// (28 cols) staged in LDS per dy; thread owns 3 x-positions x 4 out-channels.
__global__ __launch_bounds__(256) void conv5(
    const float* __restrict__ In, const float* __restrict__ Wc, const float* __restrict__ cb,
    float* __restrict__ g)
{
    __shared__ float As[28*256];
    int row = blockIdx.x;             // b*64 + y
    int z   = blockIdx.y;             // co half
    int b = row >> 6, y = row & 63;
    int tid = threadIdx.x;
    int co = z*128 + (tid & 31)*4;
    int rg = (tid >> 5) * 3;          // output x start
    float4 acc[3];
    #pragma unroll
    for (int r = 0; r < 3; ++r) acc[r] = make_float4(0.f,0.f,0.f,0.f);
    for (int dy = 0; dy < 5; ++dy) {
        int yy = y + dy - 2;
        bool rowok = (yy >= 0 && yy < 64);
        __syncthreads();
        for (int col = 0; col < 28; ++col) {
            int xx = col - 2;
            float v = 0.f;
            if (rowok && xx >= 0 && xx < 24)
                v = In[((size_t)((b*64 + yy)*24 + xx))*256 + tid];
            As[col*256 + tid] = v;
        }
        __syncthreads();
        for (int dx = 0; dx < 5; ++dx) {
            const float* Wt = Wc + ((size_t)(dy*5 + dx))*65536;
            for (int k = 0; k < 256; k += 4) {
                float4 b0 = *(const float4*)(Wt + (size_t)(k+0)*256 + co);
                float4 b1 = *(const float4*)(Wt + (size_t)(k+1)*256 + co);
                float4 b2 = *(const float4*)(Wt + (size_t)(k+2)*256 + co);
                float4 b3 = *(const float4*)(Wt + (size_t)(k+3)*256 + co);
                #pragma unroll
                for (int r = 0; r < 3; ++r) {
                    float4 a = *(const float4*)(As + (rg + r + dx)*256 + k);
                    acc[r].x += a.x*b0.x + a.y*b1.x + a.z*b2.x + a.w*b3.x;
                    acc[r].y += a.x*b0.y + a.y*b1.y + a.z*b2.y + a.w*b3.y;
                    acc[r].z += a.x*b0.z + a.y*b1.z + a.z*b2.z + a.w*b3.z;
                    acc[r].w += a.x*b0.w + a.y*b1.w + a.z*b2.w + a.w*b3.w;
                }
            }
        }
    }
    float4 cbv = *(const float4*)(cb + co);
    int posbase = row*24;
    #pragma unroll
    for (int r = 0; r < 3; ++r) {
        float4 o = acc[r];
        o.x += cbv.x; o.y += cbv.y; o.z += cbv.z; o.w += cbv.w;
        *(float4*)(g + ((size_t)(posbase + rg + r))*256 + co) = o;
    }
}

// ---------------------------------------------------------------- launcher
extern "C" void kernel_launch(void* const* d_in, const int* in_sizes, int n_in,
                              void* d_out, int out_size, void* d_ws, size_t ws_size,
                              hipStream_t stream)
{
    (void)in_sizes; (void)n_in; (void)out_size; (void)ws_size;
    const float* x    = (const float*)d_in[0];
    const float* wq   = (const float*)d_in[1];
    const float* bq   = (const float*)d_in[2];
    const float* wk   = (const float*)d_in[3];
    const float* bk   = (const float*)d_in[4];
    const float* wv   = (const float*)d_in[5];
    const float* bv   = (const float*)d_in[6];
    const float* wqa  = (const float*)d_in[7];
    const float* bqa  = (const float*)d_in[8];
    const float* wka  = (const float*)d_in[9];
    const float* bka  = (const float*)d_in[10];
    const float* wva  = (const float*)d_in[11];
    const float* bva  = (const float*)d_in[12];
    const float* woa  = (const float*)d_in[13];
    const float* boa  = (const float*)d_in[14];
    const float* cw   = (const float*)d_in[15];
    const float* cbi  = (const float*)d_in[16];
    const float* ln1g = (const float*)d_in[17];
    const float* ln1b = (const float*)d_in[18];
    const float* ln2g = (const float*)d_in[19];
    const float* ln2b = (const float*)d_in[20];
    float* out = (float*)d_out;

    float* ws = (float*)d_ws;
    float* q_p  = ws + 0ull*NE;
    float* k_p  = ws + 1ull*NE;
    float* v_p  = ws + 2ull*NE;
    float* qa   = ws + 3ull*NE;
    float* ka   = ws + 4ull*NE;
    float* va   = ws + 5ull*NE;
    float* ctx  = ws + 6ull*NE;
    float* kvs  = ws + 7ull*NE;
    float* qloc = ws + 8ull*NE;          // 4096
    float* kloc = qloc + 4096;           // 4096
    int*   Rix  = (int*)(kloc + 4096);   // 64 ints
    float* pml  = kloc + 4096 + 64;      // 128*4*192*2 = 196608
    float* pacc = pml + 196608;          // 128*4*192*32 = 3145728
    // aliases (lifetimes disjoint, stream-ordered):
    float* routing = q_p;   // wo output; q_p consumed by gemm2/locmean
    float* x_res   = qa;    // qa consumed by attn_partial
    float* g       = ka;    // ka consumed by attn_partial

    // 1. q_p/k_p/v_p projections
    gemm_k3<<<dim3(96,3), 256, 0, stream>>>(x,x,x, wq,wk,wv, bq,bk,bv, q_p,k_p,v_p);
    // 2. conv input
    addkv<<<NE/1024, 256, 0, stream>>>(k_p, v_p, kvs);
    // 3. block descriptors
    locmean<<<dim3(16,2), 256, 0, stream>>>(q_p, k_p, qloc, kloc);
    // 4. routing top-k
    topk_kern<<<2, 64, 0, stream>>>(qloc, kloc, Rix);
    // 5. attention projections (commute with gather)
    gemm_k3<<<dim3(96,3), 256, 0, stream>>>(q_p,k_p,v_p, wqa,wka,wva, bqa,bka,bva, qa,ka,va);
    // 6. attention partials (flash-style, kv-block split)
    attn_partial<<<dim3(128,4), 192, 0, stream>>>(qa, ka, va, Rix, pml, pacc);
    // 7. merge -> ctx
    attn_merge<<<NE/256, 256, 0, stream>>>(pml, pacc, ctx);
    // 8. output projection (kv-mean is identity: query copies identical)
    gemm_k3<<<dim3(96,1), 256, 0, stream>>>(ctx,ctx,ctx, woa,woa,woa, boa,boa,boa,
                                            routing,routing,routing);
    // 9. LN1(x + routing)
    ln_add<<<NPOS/4, 256, 0, stream>>>(x, routing, ln1g, ln1b, x_res);
    // 10. 5x5 SAME conv on (k_p+v_p)
    conv5<<<dim3(128,2), 256, 0, stream>>>(kvs, cw, cbi, g);
    // 11. LN2(x_res + g) -> out
    ln_add<<<NPOS/4, 256, 0, stream>>>(x_res, g, ln2g, ln2b, out);
}

// Round 3
// 397.010 us; speedup vs baseline: 1.7428x; 1.7428x over previous
//
#include <hip/hip_runtime.h>
#include <hip/hip_bf16.h>

// DRSA temporal block. Dims: B=2, P=8, hp=8, W=24, C=256, NH=8, dk=32, kv=4, H=64.
// 3072 positions, tensors [pos][256] row-major. Conv path now bf16 implicit-GEMM MFMA.

#define NPOS 3072
#define CD   256
#define NE   (NPOS*CD)

typedef short bf16x8 __attribute__((ext_vector_type(8)));  // 8 bf16 = 4 VGPRs
typedef float f32x4  __attribute__((ext_vector_type(4)));

__device__ inline ushort f2bf(float f) {
    __hip_bfloat16 h = __float2bfloat16(f);   // RNE
    return *reinterpret_cast<ushort*>(&h);
}

// ---------------------------------------------------------------- GEMM triple (unchanged)
__global__ __launch_bounds__(256) void gemm_k3(
    const float* __restrict__ A0, const float* __restrict__ A1, const float* __restrict__ A2,
    const float* __restrict__ W0, const float* __restrict__ W1, const float* __restrict__ W2,
    const float* __restrict__ B0, const float* __restrict__ B1, const float* __restrict__ B2,
    float* __restrict__ O0, float* __restrict__ O1, float* __restrict__ O2)
{
    __shared__ float As[32*256];
    int which = blockIdx.y;
    const float* A  = which==0 ? A0 : (which==1 ? A1 : A2);
    const float* Wm = which==0 ? W0 : (which==1 ? W1 : W2);
    const float* Bi = which==0 ? B0 : (which==1 ? B1 : B2);
    float*       O  = which==0 ? O0 : (which==1 ? O1 : O2);
    int tid = threadIdx.x;
    int m0 = blockIdx.x * 32;
    #pragma unroll
    for (int j = 0; j < 32; ++j)
        As[j*256 + tid] = A[(size_t)(m0 + j)*256 + tid];
    __syncthreads();
    int cq = (tid & 63) * 4;
    int rg = (tid >> 6) * 8;
    float4 acc[8];
    #pragma unroll
    for (int r = 0; r < 8; ++r) acc[r] = make_float4(0.f,0.f,0.f,0.f);
    for (int k = 0; k < 256; k += 4) {
        float4 b0 = *(const float4*)(Wm + (size_t)(k+0)*256 + cq);
        float4 b1 = *(const float4*)(Wm + (size_t)(k+1)*256 + cq);
        float4 b2 = *(const float4*)(Wm + (size_t)(k+2)*256 + cq);
        float4 b3 = *(const float4*)(Wm + (size_t)(k+3)*256 + cq);
        #pragma unroll
        for (int r = 0; r < 8; ++r) {
            float4 a = *(const float4*)(As + (rg + r)*256 + k);
            acc[r].x += a.x*b0.x + a.y*b1.x + a.z*b2.x + a.w*b3.x;
            acc[r].y += a.x*b0.y + a.y*b1.y + a.z*b2.y + a.w*b3.y;
            acc[r].z += a.x*b0.z + a.y*b1.z + a.z*b2.z + a.w*b3.z;
            acc[r].w += a.x*b0.w + a.y*b1.w + a.z*b2.w + a.w*b3.w;
        }
    }
    float4 bb = *(const float4*)(Bi + cq);
    #pragma unroll
    for (int r = 0; r < 8; ++r) {
        float4 o = acc[r];
        o.x += bb.x; o.y += bb.y; o.z += bb.z; o.w += bb.w;
        *(float4*)(O + (size_t)(m0 + rg + r)*256 + cq) = o;
    }
}

// ---------------------------------------------------------------- padded bf16 conv input
// kvb[2][68][28][256] bf16 = (k_p+v_p) with 2-halo zero padding in y and x.
__global__ __launch_bounds__(256) void addkv_pad(
    const float* __restrict__ kp, const float* __restrict__ vp, ushort* __restrict__ kvb)
{
    int t  = blockIdx.x*256 + threadIdx.x;   // 0..243711  (952 blocks)
    int ci = (t & 63) * 4;
    int p  = t >> 6;                         // 0..15231 padded positions
    int xp = p % 28;
    int r  = p / 28;
    int yp = r % 68;
    int b  = r / 68;
    int y = yp - 2, x = xp - 2;
    float4 s = make_float4(0.f,0.f,0.f,0.f);
    if (y >= 0 && y < 64 && x >= 0 && x < 24) {
        size_t base = ((size_t)((b*64 + y)*24 + x))*256 + ci;
        float4 a = *(const float4*)(kp + base);
        float4 c = *(const float4*)(vp + base);
        s.x = a.x + c.x; s.y = a.y + c.y; s.z = a.z + c.z; s.w = a.w + c.w;
    }
    ushort4 o;
    o.x = f2bf(s.x); o.y = f2bf(s.y); o.z = f2bf(s.z); o.w = f2bf(s.w);
    *(ushort4*)(kvb + (size_t)p*256 + ci) = o;
}

// ---------------------------------------------------------------- weight transpose -> bf16
// conv_w HWIO [5][5][ci][co] fp32  ->  WcT [tap][co][ci] bf16 (k-contiguous B-operand).
__global__ __launch_bounds__(256) void wtrans(
    const float* __restrict__ cw, ushort* __restrict__ wct)
{
    __shared__ float l[64*65];
    int blk = blockIdx.x;            // 25 taps * 16 tiles = 400
    int tap = blk >> 4;
    int r2  = blk & 15;
    int ci0 = (r2 >> 2) * 64;
    int co0 = (r2 & 3) * 64;
    int tid = threadIdx.x;
    int a = tid >> 6;                // 0..3
    int c = tid & 63;                // 0..63
    #pragma unroll 4
    for (int k = 0; k < 16; ++k) {
        int cil = k*4 + a;
        l[cil*65 + c] = cw[(size_t)tap*65536 + (size_t)(ci0 + cil)*256 + co0 + c];
    }
    __syncthreads();
    #pragma unroll 4
    for (int k = 0; k < 16; ++k) {
        int col = k*4 + a;
        wct[((size_t)(tap*256 + co0 + col))*256 + ci0 + c] = f2bf(l[c*65 + col]);
    }
}

// ---------------------------------------------------------------- implicit-GEMM conv (MFMA)
// Wave = (image row b*64+y, co-quarter nq, dy). K = 5 dx-taps x 256 ci.
// M-frags: padded x0 in {0,16} (x>=24 results discarded at store).
// A-frag: lane&15 = m (output row), k=(lane>>4)*8+j contiguous ci  [m89/m120-verified layout]
// B-frag: lane&15 = n (co),        k contiguous ci (WcT rows)
// D: col = lane&15 = co, row = (lane>>4)*4 + reg = m.
__global__ __launch_bounds__(256) void conv_mfma(
    const ushort* __restrict__ kvb, const ushort* __restrict__ wct,
    float* __restrict__ pconv)
{
    int tid  = threadIdx.x;
    int wid  = blockIdx.x*4 + (tid >> 6);    // 0..2559
    int lane = tid & 63;
    int lm = lane & 15, lq = lane >> 4;
    int row = wid / 20;                      // 0..127 (b*64+y)
    int rem = wid - row*20;
    int nq  = rem / 5;                       // co quarter 0..3
    int dy  = rem - nq*5;                    // 0..4
    int b = row >> 6, y = row & 63;

    // element offsets (ushort units)
    int abase = ((b*68 + y + dy)*28 + lm)*256 + lq*8;          // padded pos (b, y+dy, lm)
    int bbase = ((dy*5*256) + nq*64 + lm)*256 + lq*8;          // tap=dy*5, co=nq*64+lm

    f32x4 acc[2][4];
    #pragma unroll
    for (int i = 0; i < 2; ++i)
        #pragma unroll
        for (int j = 0; j < 4; ++j)
            acc[i][j] = (f32x4){0.f,0.f,0.f,0.f};

    for (int dx = 0; dx < 5; ++dx) {
        const ushort* ap = kvb + abase + dx*256;       // x' = lm + dx (+16 for frag 1)
        const ushort* bp = wct + bbase + dx*65536;     // tap advance = 256*256
        #pragma unroll
        for (int ch = 0; ch < 8; ++ch) {
            bf16x8 a0 = *(const bf16x8*)(ap + ch*32);
            bf16x8 a1 = *(const bf16x8*)(ap + 16*256 + ch*32);
            bf16x8 b0 = *(const bf16x8*)(bp + ch*32);
            bf16x8 b1 = *(const bf16x8*)(bp + 16*256 + ch*32);
            bf16x8 b2 = *(const bf16x8*)(bp + 32*256 + ch*32);
            bf16x8 b3 = *(const bf16x8*)(bp + 48*256 + ch*32);
            acc[0][0] = __builtin_amdgcn_mfma_f32_16x16x32_bf16(a0, b0, acc[0][0], 0, 0, 0);
            acc[0][1] = __builtin_amdgcn_mfma_f32_16x16x32_bf16(a0, b1, acc[0][1], 0, 0, 0);
            acc[0][2] = __builtin_amdgcn_mfma_f32_16x16x32_bf16(a0, b2, acc[0][2], 0, 0, 0);
            acc[0][3] = __builtin_amdgcn_mfma_f32_16x16x32_bf16(a0, b3, acc[0][3], 0, 0, 0);
            acc[1][0] = __builtin_amdgcn_mfma_f32_16x16x32_bf16(a1, b0, acc[1][0], 0, 0, 0);
            acc[1][1] = __builtin_amdgcn_mfma_f32_16x16x32_bf16(a1, b1, acc[1][1], 0, 0, 0);
            acc[1][2] = __builtin_amdgcn_mfma_f32_16x16x32_bf16(a1, b2, acc[1][2], 0, 0, 0);
            acc[1][3] = __builtin_amdgcn_mfma_f32_16x16x32_bf16(a1, b3, acc[1][3], 0, 0, 0);
        }
    }

    int cob = nq*64 + lm;
    #pragma unroll
    for (int mf = 0; mf < 2; ++mf) {
        int xb = mf*16 + lq*4;
        #pragma unroll
        for (int f = 0; f < 4; ++f) {
            #pragma unroll
            for (int r = 0; r < 4; ++r) {
                int x = xb + r;
                if (x < 24)
                    pconv[((size_t)(dy*3072 + row*24 + x))*256 + cob + f*16] = acc[mf][f][r];
            }
        }
    }
}

// ---------------------------------------------------------------- sum 5 dy-partials + bias
__global__ __launch_bounds__(256) void reduce5(
    const float* __restrict__ pc, const float* __restrict__ cb, float* __restrict__ g)
{
    int i  = (blockIdx.x*256 + threadIdx.x)*4;   // 768 blocks cover NE
    int co = i & 255;
    float4 s = *(const float4*)(cb + co);
    #pragma unroll
    for (int d = 0; d < 5; ++d) {
        float4 v = *(const float4*)(pc + (size_t)d*NE + i);
        s.x += v.x; s.y += v.y; s.z += v.z; s.w += v.w;
    }
    *(float4*)(g + i) = s;
}

// ---------------------------------------------------------------- block descriptors (unchanged)
__global__ __launch_bounds__(256) void locmean(
    const float* __restrict__ qp, const float* __restrict__ kp,
    float* __restrict__ qloc, float* __restrict__ kloc)
{
    int bp = blockIdx.x;
    int c  = threadIdx.x;
    const float* src = blockIdx.y ? kp : qp;
    float*       dst = blockIdx.y ? kloc : qloc;
    float s = 0.f;
    for (int i = 0; i < 192; ++i)
        s += src[((size_t)(bp*192 + i))*256 + c];
    dst[bp*256 + c] = s * (1.0f/192.0f);
}

// ---------------------------------------------------------------- routing top-k (unchanged)
__global__ void topk_kern(const float* __restrict__ qloc, const float* __restrict__ kloc,
                          int* __restrict__ Rix)
{
    __shared__ float S[64];
    int b = blockIdx.x, t = threadIdx.x;
    int p = t >> 3, qq = t & 7;
    float s = 0.f;
    for (int c = 0; c < 256; ++c)
        s += qloc[(b*8+p)*256 + c] * kloc[(b*8+qq)*256 + c];
    S[t] = s;
    __syncthreads();
    if (t < 8) {
        float vals[8];
        #pragma unroll
        for (int j = 0; j < 8; ++j) vals[j] = S[t*8 + j];
        for (int j = 0; j < 4; ++j) {
            int best = 0; float bv = vals[0];
            #pragma unroll
            for (int i = 1; i < 8; ++i) if (vals[i] > bv) { bv = vals[i]; best = i; }
            Rix[(b*8 + t)*4 + j] = best;
            vals[best] = -1e30f;
        }
    }
}

// ---------------------------------------------------------------- attention partials (unchanged)
__global__ __launch_bounds__(192) void attn_partial(
    const float* __restrict__ qa, const float* __restrict__ ka, const float* __restrict__ va,
    const int* __restrict__ Rix, float* __restrict__ pml, float* __restrict__ pacc)
{
    __shared__ float Ks[64*32];
    __shared__ float Vs[64*32];
    int bph = blockIdx.x;
    int kvb = blockIdx.y;
    int bp = bph >> 3, h = bph & 7;
    int b  = bp >> 3;
    int q  = threadIdx.x;
    int r  = Rix[bp*4 + kvb];
    const float* Qrow  = qa + ((size_t)(bp*192 + q))*256 + h*32;
    const float* Kbase = ka + ((size_t)((b*8 + r)*192))*256 + h*32;
    const float* Vbase = va + ((size_t)((b*8 + r)*192))*256 + h*32;
    float4 qv[8];
    #pragma unroll
    for (int i = 0; i < 8; ++i) qv[i] = *(const float4*)(Qrow + i*4);
    float4 acc[8];
    #pragma unroll
    for (int i = 0; i < 8; ++i) acc[i] = make_float4(0.f,0.f,0.f,0.f);
    float m = -1e30f, l = 0.f;
    for (int c0 = 0; c0 < 192; c0 += 64) {
        __syncthreads();
        for (int idx = threadIdx.x; idx < 1024; idx += 192) {
            int half = idx >> 9;
            int j = idx & 511;
            int key = j >> 3, d4 = (j & 7)*4;
            const float* src = (half ? Vbase : Kbase) + (size_t)(c0 + key)*256 + d4;
            float4 v = *(const float4*)src;
            float* dst = (half ? Vs : Ks) + key*32 + d4;
            *(float4*)dst = v;
        }
        __syncthreads();
        for (int key = 0; key < 64; ++key) {
            const float4* Kr = (const float4*)(Ks + key*32);
            float s = 0.f;
            #pragma unroll
            for (int i = 0; i < 8; ++i) {
                float4 kf = Kr[i];
                s += qv[i].x*kf.x + qv[i].y*kf.y + qv[i].z*kf.z + qv[i].w*kf.w;
            }
            s *= 0.17677669529663687f;
            if (s > m) {
                float corr = __expf(m - s);
                l *= corr;
                #pragma unroll
                for (int i = 0; i < 8; ++i) {
                    acc[i].x *= corr; acc[i].y *= corr; acc[i].z *= corr; acc[i].w *= corr;
                }
                m = s;
            }
            float e = __expf(s - m);
            l += e;
            const float4* Vr = (const float4*)(Vs + key*32);
            #pragma unroll
            for (int i = 0; i < 8; ++i) {
                float4 vf = Vr[i];
                acc[i].x += e*vf.x; acc[i].y += e*vf.y; acc[i].z += e*vf.z; acc[i].w += e*vf.w;
            }
        }
    }
    size_t pidx = ((size_t)(bph*4 + kvb))*192 + q;
    pml[pidx*2 + 0] = m;
    pml[pidx*2 + 1] = l;
    #pragma unroll
    for (int i = 0; i < 8; ++i)
        *(float4*)(pacc + pidx*32 + i*4) = acc[i];
}

// ---------------------------------------------------------------- merge partials (unchanged)
__global__ __launch_bounds__(256) void attn_merge(
    const float* __restrict__ pml, const float* __restrict__ pacc, float* __restrict__ ctx)
{
    int idx = blockIdx.x*256 + threadIdx.x;
    int d  = idx & 31;
    int gq = idx >> 5;
    int bph = gq / 192;
    int q = gq - bph*192;
    int bp = bph >> 3, h = bph & 7;
    float mk[4], lk[4];
    float M = -1e30f;
    #pragma unroll
    for (int k = 0; k < 4; ++k) {
        size_t p = ((size_t)(bph*4 + k))*192 + q;
        mk[k] = pml[p*2]; lk[k] = pml[p*2 + 1];
        M = fmaxf(M, mk[k]);
    }
    float wsum = 0.f, cv = 0.f;
    #pragma unroll
    for (int k = 0; k < 4; ++k) {
        float w = __expf(mk[k] - M);
        wsum += lk[k]*w;
        cv += w * pacc[(((size_t)(bph*4 + k))*192 + q)*32 + d];
    }
    ctx[((size_t)(bp*192 + q))*256 + h*32 + d] = cv / wsum;
}

// ---------------------------------------------------------------- residual + LayerNorm (unchanged)
__global__ __launch_bounds__(256) void ln_add(
    const float* __restrict__ A, const float* __restrict__ B1,
    const float* __restrict__ gamma, const float* __restrict__ beta,
    float* __restrict__ out)
{
    int pos  = blockIdx.x*4 + (threadIdx.x >> 6);
    int lane = threadIdx.x & 63;
    size_t base = (size_t)pos*256 + lane*4;
    float4 a = *(const float4*)(A + base);
    float4 b = *(const float4*)(B1 + base);
    float x0 = a.x + b.x, x1 = a.y + b.y, x2 = a.z + b.z, x3 = a.w + b.w;
    float s  = x0 + x1 + x2 + x3;
    float sq = x0*x0 + x1*x1 + x2*x2 + x3*x3;
    #pragma unroll
    for (int off = 32; off > 0; off >>= 1) {
        s  += __shfl_xor(s,  off);
        sq += __shfl_xor(sq, off);
    }
    float mean = s * (1.0f/256.0f);
    float var  = sq * (1.0f/256.0f) - mean*mean;
    float rstd = rsqrtf(var + 1e-5f);
    float4 gv = *(const float4*)(gamma + lane*4);
    float4 bv = *(const float4*)(beta  + lane*4);
    float4 o;
    o.x = (x0 - mean)*rstd*gv.x + bv.x;
    o.y = (x1 - mean)*rstd*gv.y + bv.y;
    o.z = (x2 - mean)*rstd*gv.z + bv.z;
    o.w = (x3 - mean)*rstd*gv.w + bv.w;
    *(float4*)(out + base) = o;
}

// ---------------------------------------------------------------- launcher
extern "C" void kernel_launch(void* const* d_in, const int* in_sizes, int n_in,
                              void* d_out, int out_size, void* d_ws, size_t ws_size,
                              hipStream_t stream)
{
    (void)in_sizes; (void)n_in; (void)out_size; (void)ws_size;
    const float* x    = (const float*)d_in[0];
    const float* wq   = (const float*)d_in[1];
    const float* bq   = (const float*)d_in[2];
    const float* wk   = (const float*)d_in[3];
    const float* bk   = (const float*)d_in[4];
    const float* wv   = (const float*)d_in[5];
    const float* bv   = (const float*)d_in[6];
    const float* wqa  = (const float*)d_in[7];
    const float* bqa  = (const float*)d_in[8];
    const float* wka  = (const float*)d_in[9];
    const float* bka  = (const float*)d_in[10];
    const float* wva  = (const float*)d_in[11];
    const float* bva  = (const float*)d_in[12];
    const float* woa  = (const float*)d_in[13];
    const float* boa  = (const float*)d_in[14];
    const float* cw   = (const float*)d_in[15];
    const float* cbi  = (const float*)d_in[16];
    const float* ln1g = (const float*)d_in[17];
    const float* ln1b = (const float*)d_in[18];
    const float* ln2g = (const float*)d_in[19];
    const float* ln2b = (const float*)d_in[20];
    float* out = (float*)d_out;

    // Workspace layout (float units), total 9,375,808 floats = 37.5 MB (<38.65 MB proven):
    //  [0,NE)      q_p   (later: routing)
    //  [NE,2NE)    qa    (later: x_res)
    //  [2NE,3NE)   ka    (later: g)
    //  [3NE,4NE)   va
    //  [4NE,5NE)   v_p   (later: ctx)
    //  [5NE, 5NE+4128768)  k_p | pml | pacc   (later: pconv[5][3072][256])
    //  then qloc(4096) kloc(4096) Rix(64) kvb(487424 f-slots bf16) WcT(819200 f-slots bf16)
    float* ws = (float*)d_ws;
    float* q_p  = ws + 0ull*NE;
    float* qa   = ws + 1ull*NE;
    float* ka   = ws + 2ull*NE;
    float* va   = ws + 3ull*NE;
    float* v_p  = ws + 4ull*NE;
    float* k_p  = ws + 5ull*NE;
    float* pml  = k_p + NE;                  // 196608
    float* pacc = pml + 196608;              // 3145728
    float* tail = pacc + 3145728;
    float* qloc = tail;                      // 4096
    float* kloc = qloc + 4096;               // 4096
    int*   Rix  = (int*)(kloc + 4096);       // 64
    ushort* kvb = (ushort*)(kloc + 4096 + 64);        // 974848 bf16
    ushort* wct = (ushort*)((float*)kvb + 487424);    // 1638400 bf16
    // aliases (stream-ordered disjoint lifetimes):
    float* routing = q_p;    // q_p dead after locmean + gemm#2
    float* x_res   = qa;     // qa dead after attn_partial
    float* g       = ka;     // ka dead after attn_partial
    float* ctx     = v_p;    // v_p dead after gemm#2
    float* pconv   = k_p;    // k_p/pml/pacc dead after gemm#2 / attn_merge

    // 1. q_p/k_p/v_p projections
    gemm_k3<<<dim3(96,3), 256, 0, stream>>>(x,x,x, wq,wk,wv, bq,bk,bv, q_p,k_p,v_p);
    // 2. padded bf16 conv input, 3. bf16 transposed conv weights
    addkv_pad<<<952, 256, 0, stream>>>(k_p, v_p, kvb);
    wtrans<<<400, 256, 0, stream>>>(cw, wct);
    // 4. block descriptors, 5. routing top-k
    locmean<<<dim3(16,2), 256, 0, stream>>>(q_p, k_p, qloc, kloc);
    topk_kern<<<2, 64, 0, stream>>>(qloc, kloc, Rix);
    // 6. attention projections (commute with gather)
    gemm_k3<<<dim3(96,3), 256, 0, stream>>>(q_p,k_p,v_p, wqa,wka,wva, bqa,bka,bva, qa,ka,va);
    // 7. attention partials, 8. merge
    attn_partial<<<dim3(128,4), 192, 0, stream>>>(qa, ka, va, Rix, pml, pacc);
    attn_merge<<<NE/256, 256, 0, stream>>>(pml, pacc, ctx);
    // 9. output projection (kv-mean is identity: query copies identical)
    gemm_k3<<<dim3(96,1), 256, 0, stream>>>(ctx,ctx,ctx, woa,woa,woa, boa,boa,boa,
                                            routing,routing,routing);
    // 10. LN1(x + routing)
    ln_add<<<NPOS/4, 256, 0, stream>>>(x, routing, ln1g, ln1b, x_res);
    // 11. conv as implicit-GEMM MFMA (dy-split partials into dead k_p/pml/pacc region)
    conv_mfma<<<640, 256, 0, stream>>>(kvb, wct, pconv);
    // 12. sum dy-partials + bias -> g
    reduce5<<<768, 256, 0, stream>>>(pconv, cbi, g);
    // 13. LN2(x_res + g) -> out
    ln_add<<<NPOS/4, 256, 0, stream>>>(x_res, g, ln2g, ln2b, out);
}

// Round 4
// 315.367 us; speedup vs baseline: 2.1940x; 1.2589x over previous
//
#include <hip/hip_runtime.h>
#include <hip/hip_bf16.h>

// DRSA temporal block. B=2, P=8, hp=8, W=24, C=256, NH=8, dk=32, kv=4, H=64.
// 3072 positions, [pos][256] row-major. Conv + attention on bf16 MFMA.

#define NPOS 3072
#define CD   256
#define NE   (NPOS*CD)

typedef short bf16x8 __attribute__((ext_vector_type(8)));
typedef float f32x4  __attribute__((ext_vector_type(4)));

__device__ inline ushort f2bf(float f) {
    __hip_bfloat16 h = __float2bfloat16(f);   // RNE
    return *reinterpret_cast<ushort*>(&h);
}

// ---------------------------------------------------------------- GEMM triple fp32 (proj + wo)
__global__ __launch_bounds__(256) void gemm_k3(
    const float* __restrict__ A0, const float* __restrict__ A1, const float* __restrict__ A2,
    const float* __restrict__ W0, const float* __restrict__ W1, const float* __restrict__ W2,
    const float* __restrict__ B0, const float* __restrict__ B1, const float* __restrict__ B2,
    float* __restrict__ O0, float* __restrict__ O1, float* __restrict__ O2)
{
    __shared__ float As[32*256];
    int which = blockIdx.y;
    const float* A  = which==0 ? A0 : (which==1 ? A1 : A2);
    const float* Wm = which==0 ? W0 : (which==1 ? W1 : W2);
    const float* Bi = which==0 ? B0 : (which==1 ? B1 : B2);
    float*       O  = which==0 ? O0 : (which==1 ? O1 : O2);
    int tid = threadIdx.x;
    int m0 = blockIdx.x * 32;
    #pragma unroll
    for (int j = 0; j < 32; ++j)
        As[j*256 + tid] = A[(size_t)(m0 + j)*256 + tid];
    __syncthreads();
    int cq = (tid & 63) * 4;
    int rg = (tid >> 6) * 8;
    float4 acc[8];
    #pragma unroll
    for (int r = 0; r < 8; ++r) acc[r] = make_float4(0.f,0.f,0.f,0.f);
    for (int k = 0; k < 256; k += 4) {
        float4 b0 = *(const float4*)(Wm + (size_t)(k+0)*256 + cq);
        float4 b1 = *(const float4*)(Wm + (size_t)(k+1)*256 + cq);
        float4 b2 = *(const float4*)(Wm + (size_t)(k+2)*256 + cq);
        float4 b3 = *(const float4*)(Wm + (size_t)(k+3)*256 + cq);
        #pragma unroll
        for (int r = 0; r < 8; ++r) {
            float4 a = *(const float4*)(As + (rg + r)*256 + k);
            acc[r].x += a.x*b0.x + a.y*b1.x + a.z*b2.x + a.w*b3.x;
            acc[r].y += a.x*b0.y + a.y*b1.y + a.z*b2.y + a.w*b3.y;
            acc[r].z += a.x*b0.z + a.y*b1.z + a.z*b2.z + a.w*b3.z;
            acc[r].w += a.x*b0.w + a.y*b1.w + a.z*b2.w + a.w*b3.w;
        }
    }
    float4 bb = *(const float4*)(Bi + cq);
    #pragma unroll
    for (int r = 0; r < 8; ++r) {
        float4 o = acc[r];
        o.x += bb.x; o.y += bb.y; o.z += bb.z; o.w += bb.w;
        *(float4*)(O + (size_t)(m0 + rg + r)*256 + cq) = o;
    }
}

// ---------------------------------------------------------------- GEMM triple, bf16 out
// which==0 (qab) additionally scaled by 1/sqrt(dk) so attention needs no score scale.
__global__ __launch_bounds__(256) void gemm_k3b(
    const float* __restrict__ A0, const float* __restrict__ A1, const float* __restrict__ A2,
    const float* __restrict__ W0, const float* __restrict__ W1, const float* __restrict__ W2,
    const float* __restrict__ B0, const float* __restrict__ B1, const float* __restrict__ B2,
    ushort* __restrict__ O0, ushort* __restrict__ O1, ushort* __restrict__ O2)
{
    __shared__ float As[32*256];
    int which = blockIdx.y;
    const float* A  = which==0 ? A0 : (which==1 ? A1 : A2);
    const float* Wm = which==0 ? W0 : (which==1 ? W1 : W2);
    const float* Bi = which==0 ? B0 : (which==1 ? B1 : B2);
    ushort*      O  = which==0 ? O0 : (which==1 ? O1 : O2);
    float sc = which==0 ? 0.17677669529663687f : 1.0f;
    int tid = threadIdx.x;
    int m0 = blockIdx.x * 32;
    #pragma unroll
    for (int j = 0; j < 32; ++j)
        As[j*256 + tid] = A[(size_t)(m0 + j)*256 + tid];
    __syncthreads();
    int cq = (tid & 63) * 4;
    int rg = (tid >> 6) * 8;
    float4 acc[8];
    #pragma unroll
    for (int r = 0; r < 8; ++r) acc[r] = make_float4(0.f,0.f,0.f,0.f);
    for (int k = 0; k < 256; k += 4) {
        float4 b0 = *(const float4*)(Wm + (size_t)(k+0)*256 + cq);
        float4 b1 = *(const float4*)(Wm + (size_t)(k+1)*256 + cq);
        float4 b2 = *(const float4*)(Wm + (size_t)(k+2)*256 + cq);
        float4 b3 = *(const float4*)(Wm + (size_t)(k+3)*256 + cq);
        #pragma unroll
        for (int r = 0; r < 8; ++r) {
            float4 a = *(const float4*)(As + (rg + r)*256 + k);
            acc[r].x += a.x*b0.x + a.y*b1.x + a.z*b2.x + a.w*b3.x;
            acc[r].y += a.x*b0.y + a.y*b1.y + a.z*b2.y + a.w*b3.y;
            acc[r].z += a.x*b0.z + a.y*b1.z + a.z*b2.z + a.w*b3.z;
            acc[r].w += a.x*b0.w + a.y*b1.w + a.z*b2.w + a.w*b3.w;
        }
    }
    float4 bb = *(const float4*)(Bi + cq);
    #pragma unroll
    for (int r = 0; r < 8; ++r) {
        ushort4 o;
        o.x = f2bf((acc[r].x + bb.x)*sc);
        o.y = f2bf((acc[r].y + bb.y)*sc);
        o.z = f2bf((acc[r].z + bb.z)*sc);
        o.w = f2bf((acc[r].w + bb.w)*sc);
        *(ushort4*)(O + (size_t)(m0 + rg + r)*256 + cq) = o;
    }
}

// ---------------------------------------------------------------- V transpose per (bp,h)
// vab [3072][256] bf16 -> vt [bp*8+h][dk=32][pos=192] bf16 (PV B-operand, key-contiguous).
__global__ __launch_bounds__(256) void vtrans(
    const ushort* __restrict__ vab, ushort* __restrict__ vt)
{
    __shared__ ushort L[192*36];
    int bph = blockIdx.x;            // bp*8 + h
    int bp = bph >> 3, h = bph & 7;
    int t = threadIdx.x;
    #pragma unroll
    for (int i = 0; i < 6; ++i) {
        int idx = i*256 + t;         // 1536 ushort4 total
        int pos = idx >> 3, c4 = (idx & 7)*4;
        ushort4 v = *(const ushort4*)(vab + ((size_t)(bp*192 + pos))*256 + h*32 + c4);
        *(ushort4*)(L + pos*36 + c4) = v;
    }
    __syncthreads();
    int dk = t >> 3, seg = t & 7;
    size_t ob = ((size_t)bph*32 + dk)*192 + seg*24;
    #pragma unroll
    for (int j = 0; j < 6; ++j) {
        int p0 = seg*24 + j*4;
        ushort4 o;
        o.x = L[(p0+0)*36 + dk];
        o.y = L[(p0+1)*36 + dk];
        o.z = L[(p0+2)*36 + dk];
        o.w = L[(p0+3)*36 + dk];
        *(ushort4*)(vt + ob + j*4) = o;
    }
}

// ---------------------------------------------------------------- MFMA flash attention
// grid (128 = bp*8+h, 4 = kvb), 256 thr = 4 waves. Wave w owns queries w*48..w*48+47
// (3 q-tiles of 16). Keys: 192 of routed block r, in 32-key chunks.
// S^T = mfma(K,Q): col=lane&15=query, row=quad*4+reg=key. No max-subtraction:
// |s|<~1.5 so exp is safe; softmax = (sum e*v)/(sum e) exactly.
// P^T -> A-layout via wave-private LDS tile (no barriers).
__global__ __launch_bounds__(256) void attn_mfma(
    const ushort* __restrict__ qab, const ushort* __restrict__ kab,
    const ushort* __restrict__ vt, const int* __restrict__ Rix,
    float* __restrict__ pl, float* __restrict__ pacc)
{
    __shared__ ushort P[4][16*40];    // per-wave P tile, stride 40 shorts
    int tid = threadIdx.x, w = tid >> 6, lane = tid & 63;
    int lm = lane & 15, lq = lane >> 4;
    int bph = blockIdx.x, kvb = blockIdx.y;
    int bp = bph >> 3, h = bph & 7, b = bp >> 3;
    int r = Rix[bp*4 + kvb];

    bf16x8 qf[3];
    #pragma unroll
    for (int t = 0; t < 3; ++t)
        qf[t] = *(const bf16x8*)(qab + ((size_t)(bp*192 + w*48 + t*16 + lm))*256 + h*32 + lq*8);

    const ushort* kbase = kab + ((size_t)((b*8 + r)*192))*256 + h*32 + lq*8;
    const ushort* vbase = vt + ((size_t)((b*8 + r)*8 + h))*32*192 + lq*8;
    ushort* pw = P[w];

    f32x4 O[3][2];
    #pragma unroll
    for (int t = 0; t < 3; ++t) { O[t][0] = (f32x4){0,0,0,0}; O[t][1] = (f32x4){0,0,0,0}; }
    float l[3] = {0.f, 0.f, 0.f};

    for (int k0 = 0; k0 < 192; k0 += 32) {
        bf16x8 kf0 = *(const bf16x8*)(kbase + (size_t)(k0 + lm)*256);
        bf16x8 kf1 = *(const bf16x8*)(kbase + (size_t)(k0 + 16 + lm)*256);
        bf16x8 vf0 = *(const bf16x8*)(vbase + (size_t)(lm)*192 + k0);        // dk 0..15
        bf16x8 vf1 = *(const bf16x8*)(vbase + (size_t)(16 + lm)*192 + k0);   // dk 16..31
        #pragma unroll
        for (int t = 0; t < 3; ++t) {
            f32x4 s0 = __builtin_amdgcn_mfma_f32_16x16x32_bf16(kf0, qf[t], (f32x4){0,0,0,0}, 0,0,0);
            f32x4 s1 = __builtin_amdgcn_mfma_f32_16x16x32_bf16(kf1, qf[t], (f32x4){0,0,0,0}, 0,0,0);
            float p0[4], p1[4];
            #pragma unroll
            for (int j = 0; j < 4; ++j) { p0[j] = __expf(s0[j]); p1[j] = __expf(s1[j]); }
            l[t] += p0[0]+p0[1]+p0[2]+p0[3] + p1[0]+p1[1]+p1[2]+p1[3];
            ushort4 a, c;
            a.x = f2bf(p0[0]); a.y = f2bf(p0[1]); a.z = f2bf(p0[2]); a.w = f2bf(p0[3]);
            c.x = f2bf(p1[0]); c.y = f2bf(p1[1]); c.z = f2bf(p1[2]); c.w = f2bf(p1[3]);
            *(ushort4*)(pw + lm*40 + lq*4)      = a;   // keys k0 + lq*4+reg
            *(ushort4*)(pw + lm*40 + 16 + lq*4) = c;   // keys k0+16 + lq*4+reg
            bf16x8 pf = *(const bf16x8*)(pw + lm*40 + lq*8);  // A[m=query lm][k=8 keys]
            O[t][0] = __builtin_amdgcn_mfma_f32_16x16x32_bf16(pf, vf0, O[t][0], 0,0,0);
            O[t][1] = __builtin_amdgcn_mfma_f32_16x16x32_bf16(pf, vf1, O[t][1], 0,0,0);
        }
    }

    #pragma unroll
    for (int t = 0; t < 3; ++t) {
        float lt = l[t];
        lt += __shfl_xor(lt, 16);
        lt += __shfl_xor(lt, 32);
        size_t pbase = ((size_t)(bph*4 + kvb))*192 + w*48 + t*16;
        if (lq == 0) pl[pbase + lm] = lt;
        #pragma unroll
        for (int nt = 0; nt < 2; ++nt)
            #pragma unroll
            for (int reg = 0; reg < 4; ++reg)
                pacc[(pbase + lq*4 + reg)*32 + nt*16 + lm] = O[t][nt][reg];
    }
}

// ---------------------------------------------------------------- merge kv-partials -> ctx
__global__ __launch_bounds__(256) void attn_merge2(
    const float* __restrict__ pl, const float* __restrict__ pacc, float* __restrict__ ctx)
{
    int idx = blockIdx.x*256 + threadIdx.x;
    int d  = idx & 31;
    int gq = idx >> 5;
    int bph = gq / 192;
    int q = gq - bph*192;
    int bp = bph >> 3, h = bph & 7;
    float ls = 0.f, cv = 0.f;
    #pragma unroll
    for (int k = 0; k < 4; ++k) {
        size_t p = ((size_t)(bph*4 + k))*192 + q;
        ls += pl[p];
        cv += pacc[p*32 + d];
    }
    ctx[((size_t)(bp*192 + q))*256 + h*32 + d] = cv / ls;
}

// ---------------------------------------------------------------- padded bf16 conv input
__global__ __launch_bounds__(256) void addkv_pad(
    const float* __restrict__ kp, const float* __restrict__ vp, ushort* __restrict__ kvb)
{
    int t  = blockIdx.x*256 + threadIdx.x;
    int ci = (t & 63) * 4;
    int p  = t >> 6;
    int xp = p % 28;
    int rr = p / 28;
    int yp = rr % 68;
    int b  = rr / 68;
    int y = yp - 2, x = xp - 2;
    float4 s = make_float4(0.f,0.f,0.f,0.f);
    if (y >= 0 && y < 64 && x >= 0 && x < 24) {
        size_t base = ((size_t)((b*64 + y)*24 + x))*256 + ci;
        float4 a = *(const float4*)(kp + base);
        float4 c = *(const float4*)(vp + base);
        s.x = a.x + c.x; s.y = a.y + c.y; s.z = a.z + c.z; s.w = a.w + c.w;
    }
    ushort4 o;
    o.x = f2bf(s.x); o.y = f2bf(s.y); o.z = f2bf(s.z); o.w = f2bf(s.w);
    *(ushort4*)(kvb + (size_t)p*256 + ci) = o;
}

// ---------------------------------------------------------------- conv weight transpose
__global__ __launch_bounds__(256) void wtrans(
    const float* __restrict__ cw, ushort* __restrict__ wct)
{
    __shared__ float l[64*65];
    int blk = blockIdx.x;
    int tap = blk >> 4;
    int r2  = blk & 15;
    int ci0 = (r2 >> 2) * 64;
    int co0 = (r2 & 3) * 64;
    int tid = threadIdx.x;
    int a = tid >> 6;
    int c = tid & 63;
    #pragma unroll 4
    for (int k = 0; k < 16; ++k) {
        int cil = k*4 + a;
        l[cil*65 + c] = cw[(size_t)tap*65536 + (size_t)(ci0 + cil)*256 + co0 + c];
    }
    __syncthreads();
    #pragma unroll 4
    for (int k = 0; k < 16; ++k) {
        int col = k*4 + a;
        wct[((size_t)(tap*256 + co0 + col))*256 + ci0 + c] = f2bf(l[c*65 + col]);
    }
}

// ---------------------------------------------------------------- implicit-GEMM conv (MFMA)
__global__ __launch_bounds__(256) void conv_mfma(
    const ushort* __restrict__ kvb, const ushort* __restrict__ wct,
    float* __restrict__ pconv)
{
    int tid  = threadIdx.x;
    int wid  = blockIdx.x*4 + (tid >> 6);
    int lane = tid & 63;
    int lm = lane & 15, lq = lane >> 4;
    int row = wid / 20;
    int rem = wid - row*20;
    int nq  = rem / 5;
    int dy  = rem - nq*5;
    int b = row >> 6, y = row & 63;

    int abase = ((b*68 + y + dy)*28 + lm)*256 + lq*8;
    int bbase = ((dy*5*256) + nq*64 + lm)*256 + lq*8;

    f32x4 acc[2][4];
    #pragma unroll
    for (int i = 0; i < 2; ++i)
        #pragma unroll
        for (int j = 0; j < 4; ++j)
            acc[i][j] = (f32x4){0.f,0.f,0.f,0.f};

    for (int dx = 0; dx < 5; ++dx) {
        const ushort* ap = kvb + abase + dx*256;
        const ushort* bp = wct + bbase + dx*65536;
        #pragma unroll
        for (int ch = 0; ch < 8; ++ch) {
            bf16x8 a0 = *(const bf16x8*)(ap + ch*32);
            bf16x8 a1 = *(const bf16x8*)(ap + 16*256 + ch*32);
            bf16x8 b0 = *(const bf16x8*)(bp + ch*32);
            bf16x8 b1 = *(const bf16x8*)(bp + 16*256 + ch*32);
            bf16x8 b2 = *(const bf16x8*)(bp + 32*256 + ch*32);
            bf16x8 b3 = *(const bf16x8*)(bp + 48*256 + ch*32);
            acc[0][0] = __builtin_amdgcn_mfma_f32_16x16x32_bf16(a0, b0, acc[0][0], 0, 0, 0);
            acc[0][1] = __builtin_amdgcn_mfma_f32_16x16x32_bf16(a0, b1, acc[0][1], 0, 0, 0);
            acc[0][2] = __builtin_amdgcn_mfma_f32_16x16x32_bf16(a0, b2, acc[0][2], 0, 0, 0);
            acc[0][3] = __builtin_amdgcn_mfma_f32_16x16x32_bf16(a0, b3, acc[0][3], 0, 0, 0);
            acc[1][0] = __builtin_amdgcn_mfma_f32_16x16x32_bf16(a1, b0, acc[1][0], 0, 0, 0);
            acc[1][1] = __builtin_amdgcn_mfma_f32_16x16x32_bf16(a1, b1, acc[1][1], 0, 0, 0);
            acc[1][2] = __builtin_amdgcn_mfma_f32_16x16x32_bf16(a1, b2, acc[1][2], 0, 0, 0);
            acc[1][3] = __builtin_amdgcn_mfma_f32_16x16x32_bf16(a1, b3, acc[1][3], 0, 0, 0);
        }
    }

    int cob = nq*64 + lm;
    #pragma unroll
    for (int mf = 0; mf < 2; ++mf) {
        int xb = mf*16 + lq*4;
        #pragma unroll
        for (int f = 0; f < 4; ++f) {
            #pragma unroll
            for (int r = 0; r < 4; ++r) {
                int x = xb + r;
                if (x < 24)
                    pconv[((size_t)(dy*3072 + row*24 + x))*256 + cob + f*16] = acc[mf][f][r];
            }
        }
    }
}

// ---------------------------------------------------------------- sum 5 dy-partials + bias
__global__ __launch_bounds__(256) void reduce5(
    const float* __restrict__ pc, const float* __restrict__ cb, float* __restrict__ g)
{
    int i  = (blockIdx.x*256 + threadIdx.x)*4;
    int co = i & 255;
    float4 s = *(const float4*)(cb + co);
    #pragma unroll
    for (int d = 0; d < 5; ++d) {
        float4 v = *(const float4*)(pc + (size_t)d*NE + i);
        s.x += v.x; s.y += v.y; s.z += v.z; s.w += v.w;
    }
    *(float4*)(g + i) = s;
}

// ---------------------------------------------------------------- block descriptors
__global__ __launch_bounds__(256) void locmean(
    const float* __restrict__ qp, const float* __restrict__ kp,
    float* __restrict__ qloc, float* __restrict__ kloc)
{
    int bp = blockIdx.x;
    int c  = threadIdx.x;
    const float* src = blockIdx.y ? kp : qp;
    float*       dst = blockIdx.y ? kloc : qloc;
    float s = 0.f;
    for (int i = 0; i < 192; ++i)
        s += src[((size_t)(bp*192 + i))*256 + c];
    dst[bp*256 + c] = s * (1.0f/192.0f);
}

// ---------------------------------------------------------------- routing top-k
__global__ void topk_kern(const float* __restrict__ qloc, const float* __restrict__ kloc,
                          int* __restrict__ Rix)
{
    __shared__ float S[64];
    int b = blockIdx.x, t = threadIdx.x;
    int p = t >> 3, qq = t & 7;
    float s = 0.f;
    for (int c = 0; c < 256; ++c)
        s += qloc[(b*8+p)*256 + c] * kloc[(b*8+qq)*256 + c];
    S[t] = s;
    __syncthreads();
    if (t < 8) {
        float vals[8];
        #pragma unroll
        for (int j = 0; j < 8; ++j) vals[j] = S[t*8 + j];
        for (int j = 0; j < 4; ++j) {
            int best = 0; float bv = vals[0];
            #pragma unroll
            for (int i = 1; i < 8; ++i) if (vals[i] > bv) { bv = vals[i]; best = i; }
            Rix[(b*8 + t)*4 + j] = best;
            vals[best] = -1e30f;
        }
    }
}

// ---------------------------------------------------------------- residual + LayerNorm
__global__ __launch_bounds__(256) void ln_add(
    const float* __restrict__ A, const float* __restrict__ B1,
    const float* __restrict__ gamma, const float* __restrict__ beta,
    float* __restrict__ out)
{
    int pos  = blockIdx.x*4 + (threadIdx.x >> 6);
    int lane = threadIdx.x & 63;
    size_t base = (size_t)pos*256 + lane*4;
    float4 a = *(const float4*)(A + base);
    float4 b = *(const float4*)(B1 + base);
    float x0 = a.x + b.x, x1 = a.y + b.y, x2 = a.z + b.z, x3 = a.w + b.w;
    float s  = x0 + x1 + x2 + x3;
    float sq = x0*x0 + x1*x1 + x2*x2 + x3*x3;
    #pragma unroll
    for (int off = 32; off > 0; off >>= 1) {
        s  += __shfl_xor(s,  off);
        sq += __shfl_xor(sq, off);
    }
    float mean = s * (1.0f/256.0f);
    float var  = sq * (1.0f/256.0f) - mean*mean;
    float rstd = rsqrtf(var + 1e-5f);
    float4 gv = *(const float4*)(gamma + lane*4);
    float4 bv = *(const float4*)(beta  + lane*4);
    float4 o;
    o.x = (x0 - mean)*rstd*gv.x + bv.x;
    o.y = (x1 - mean)*rstd*gv.y + bv.y;
    o.z = (x2 - mean)*rstd*gv.z + bv.z;
    o.w = (x3 - mean)*rstd*gv.w + bv.w;
    *(float4*)(out + base) = o;
}

// ---------------------------------------------------------------- launcher
extern "C" void kernel_launch(void* const* d_in, const int* in_sizes, int n_in,
                              void* d_out, int out_size, void* d_ws, size_t ws_size,
                              hipStream_t stream)
{
    (void)in_sizes; (void)n_in; (void)out_size; (void)ws_size;
    const float* x    = (const float*)d_in[0];
    const float* wq   = (const float*)d_in[1];
    const float* bq   = (const float*)d_in[2];
    const float* wk   = (const float*)d_in[3];
    const float* bk   = (const float*)d_in[4];
    const float* wv   = (const float*)d_in[5];
    const float* bv   = (const float*)d_in[6];
    const float* wqa  = (const float*)d_in[7];
    const float* bqa  = (const float*)d_in[8];
    const float* wka  = (const float*)d_in[9];
    const float* bka  = (const float*)d_in[10];
    const float* wva  = (const float*)d_in[11];
    const float* bva  = (const float*)d_in[12];
    const float* woa  = (const float*)d_in[13];
    const float* boa  = (const float*)d_in[14];
    const float* cw   = (const float*)d_in[15];
    const float* cbi  = (const float*)d_in[16];
    const float* ln1g = (const float*)d_in[17];
    const float* ln1b = (const float*)d_in[18];
    const float* ln2g = (const float*)d_in[19];
    const float* ln2b = (const float*)d_in[20];
    float* out = (float*)d_out;

    // Workspace (floats), total 9,179,200 f = 36.7 MB (<38.6 proven):
    //  [0,NE)        q_p      -> routing (gemm3, after q_p dead)
    //  [NE,2NE)      k_p      -> x_res   (ln1, after k_p dead)
    //  [2NE,3NE)     v_p      -> g       (reduce5, after v_p dead)
    //  [3NE,4NE)     qab|kab bf16 -> ctx fp32 (merge, after attn)
    //  [4NE,4.5NE)   vab bf16 -> pl (attn, after vtrans)
    //  [4.5NE,5NE)   vt bf16
    //  [5NE,9NE)     pacc     -> pconv [5NE,10NE) (conv after merge)
    //  [10NE,...)    kvb bf16(487424f) | wct bf16(819200f) | qloc|kloc|Rix
    float* ws = (float*)d_ws;
    float* q_p  = ws + 0ull*NE;
    float* k_p  = ws + 1ull*NE;
    float* v_p  = ws + 2ull*NE;
    ushort* qab = (ushort*)(ws + 3ull*NE);
    ushort* kab = qab + NE;
    ushort* vab = (ushort*)(ws + 4ull*NE);
    ushort* vt  = (ushort*)(ws + 4ull*NE + NE/2);
    float* pacc = ws + 5ull*NE;
    ushort* kvb = (ushort*)(ws + 10ull*NE);
    ushort* wct = (ushort*)(ws + 10ull*NE + 487424);
    float* qloc = ws + 10ull*NE + 487424 + 819200;
    float* kloc = qloc + 4096;
    int*   Rix  = (int*)(kloc + 4096);
    // aliases (stream-ordered disjoint lifetimes):
    float* routing = q_p;
    float* x_res   = k_p;
    float* g       = v_p;
    float* ctx     = (float*)qab;        // [3NE,4NE), qab+kab dead after attn
    float* pl      = (float*)vab;        // vab dead after vtrans; 98304 floats
    float* pconv   = pacc;               // [5NE,10NE), pacc dead after merge

    // 1. q/k/v projections (fp32 — routing top-k needs exact scores)
    gemm_k3<<<dim3(96,3), 256, 0, stream>>>(x,x,x, wq,wk,wv, bq,bk,bv, q_p,k_p,v_p);
    // 2-3. conv input + weights (bf16)
    addkv_pad<<<952, 256, 0, stream>>>(k_p, v_p, kvb);
    wtrans<<<400, 256, 0, stream>>>(cw, wct);
    // 4-5. routing
    locmean<<<dim3(16,2), 256, 0, stream>>>(q_p, k_p, qloc, kloc);
    topk_kern<<<2, 64, 0, stream>>>(qloc, kloc, Rix);
    // 6. attention projections -> bf16 (qab pre-scaled by 1/sqrt(dk))
    gemm_k3b<<<dim3(96,3), 256, 0, stream>>>(q_p,k_p,v_p, wqa,wka,wva, bqa,bka,bva, qab,kab,vab);
    // 7. V transpose for PV B-operand
    vtrans<<<128, 256, 0, stream>>>(vab, vt);
    // 8. MFMA flash attention (kv-split partials)
    attn_mfma<<<dim3(128,4), 256, 0, stream>>>(qab, kab, vt, Rix, pl, pacc);
    // 9. merge -> ctx
    attn_merge2<<<NE/256, 256, 0, stream>>>(pl, pacc, ctx);
    // 10. output projection (kv-mean is identity)
    gemm_k3<<<dim3(96,1), 256, 0, stream>>>(ctx,ctx,ctx, woa,woa,woa, boa,boa,boa,
                                            routing,routing,routing);
    // 11. LN1(x + routing)
    ln_add<<<NPOS/4, 256, 0, stream>>>(x, routing, ln1g, ln1b, x_res);
    // 12-13. conv (implicit-GEMM MFMA) + reduce
    conv_mfma<<<640, 256, 0, stream>>>(kvb, wct, pconv);
    reduce5<<<768, 256, 0, stream>>>(pconv, cbi, g);
    // 14. LN2(x_res + g) -> out
    ln_add<<<NPOS/4, 256, 0, stream>>>(x_res, g, ln2g, ln2b, out);
}

// Round 5
// 275.641 us; speedup vs baseline: 2.5102x; 1.1441x over previous
//
#include <hip/hip_runtime.h>
#include <hip/hip_bf16.h>

// DRSA temporal block. B=2, P=8, hp=8, W=24, C=256, NH=8, dk=32, kv=4, H=64.
// 3072 positions, [pos][256] row-major. Conv + attention on bf16 MFMA.

#define NPOS 3072
#define CD   256
#define NE   (NPOS*CD)

typedef short bf16x8 __attribute__((ext_vector_type(8)));
typedef float f32x4  __attribute__((ext_vector_type(4)));

__device__ inline ushort f2bf(float f) {
    __hip_bfloat16 h = __float2bfloat16(f);   // RNE
    return *reinterpret_cast<ushort*>(&h);
}

// ---------------------------------------------------------------- GEMM triple fp32 (proj + wo)
__global__ __launch_bounds__(256) void gemm_k3(
    const float* __restrict__ A0, const float* __restrict__ A1, const float* __restrict__ A2,
    const float* __restrict__ W0, const float* __restrict__ W1, const float* __restrict__ W2,
    const float* __restrict__ B0, const float* __restrict__ B1, const float* __restrict__ B2,
    float* __restrict__ O0, float* __restrict__ O1, float* __restrict__ O2)
{
    __shared__ float As[32*256];
    int which = blockIdx.y;
    const float* A  = which==0 ? A0 : (which==1 ? A1 : A2);
    const float* Wm = which==0 ? W0 : (which==1 ? W1 : W2);
    const float* Bi = which==0 ? B0 : (which==1 ? B1 : B2);
    float*       O  = which==0 ? O0 : (which==1 ? O1 : O2);
    int tid = threadIdx.x;
    int m0 = blockIdx.x * 32;
    #pragma unroll
    for (int j = 0; j < 32; ++j)
        As[j*256 + tid] = A[(size_t)(m0 + j)*256 + tid];
    __syncthreads();
    int cq = (tid & 63) * 4;
    int rg = (tid >> 6) * 8;
    float4 acc[8];
    #pragma unroll
    for (int r = 0; r < 8; ++r) acc[r] = make_float4(0.f,0.f,0.f,0.f);
    for (int k = 0; k < 256; k += 4) {
        float4 b0 = *(const float4*)(Wm + (size_t)(k+0)*256 + cq);
        float4 b1 = *(const float4*)(Wm + (size_t)(k+1)*256 + cq);
        float4 b2 = *(const float4*)(Wm + (size_t)(k+2)*256 + cq);
        float4 b3 = *(const float4*)(Wm + (size_t)(k+3)*256 + cq);
        #pragma unroll
        for (int r = 0; r < 8; ++r) {
            float4 a = *(const float4*)(As + (rg + r)*256 + k);
            acc[r].x += a.x*b0.x + a.y*b1.x + a.z*b2.x + a.w*b3.x;
            acc[r].y += a.x*b0.y + a.y*b1.y + a.z*b2.y + a.w*b3.y;
            acc[r].z += a.x*b0.z + a.y*b1.z + a.z*b2.z + a.w*b3.z;
            acc[r].w += a.x*b0.w + a.y*b1.w + a.z*b2.w + a.w*b3.w;
        }
    }
    float4 bb = *(const float4*)(Bi + cq);
    #pragma unroll
    for (int r = 0; r < 8; ++r) {
        float4 o = acc[r];
        o.x += bb.x; o.y += bb.y; o.z += bb.z; o.w += bb.w;
        *(float4*)(O + (size_t)(m0 + rg + r)*256 + cq) = o;
    }
}

// ---------------------------------------------------------------- GEMM triple, bf16 out
// which==0 (qab) additionally scaled by 1/sqrt(dk) so attention needs no score scale.
__global__ __launch_bounds__(256) void gemm_k3b(
    const float* __restrict__ A0, const float* __restrict__ A1, const float* __restrict__ A2,
    const float* __restrict__ W0, const float* __restrict__ W1, const float* __restrict__ W2,
    const float* __restrict__ B0, const float* __restrict__ B1, const float* __restrict__ B2,
    ushort* __restrict__ O0, ushort* __restrict__ O1, ushort* __restrict__ O2)
{
    __shared__ float As[32*256];
    int which = blockIdx.y;
    const float* A  = which==0 ? A0 : (which==1 ? A1 : A2);
    const float* Wm = which==0 ? W0 : (which==1 ? W1 : W2);
    const float* Bi = which==0 ? B0 : (which==1 ? B1 : B2);
    ushort*      O  = which==0 ? O0 : (which==1 ? O1 : O2);
    float sc = which==0 ? 0.17677669529663687f : 1.0f;
    int tid = threadIdx.x;
    int m0 = blockIdx.x * 32;
    #pragma unroll
    for (int j = 0; j < 32; ++j)
        As[j*256 + tid] = A[(size_t)(m0 + j)*256 + tid];
    __syncthreads();
    int cq = (tid & 63) * 4;
    int rg = (tid >> 6) * 8;
    float4 acc[8];
    #pragma unroll
    for (int r = 0; r < 8; ++r) acc[r] = make_float4(0.f,0.f,0.f,0.f);
    for (int k = 0; k < 256; k += 4) {
        float4 b0 = *(const float4*)(Wm + (size_t)(k+0)*256 + cq);
        float4 b1 = *(const float4*)(Wm + (size_t)(k+1)*256 + cq);
        float4 b2 = *(const float4*)(Wm + (size_t)(k+2)*256 + cq);
        float4 b3 = *(const float4*)(Wm + (size_t)(k+3)*256 + cq);
        #pragma unroll
        for (int r = 0; r < 8; ++r) {
            float4 a = *(const float4*)(As + (rg + r)*256 + k);
            acc[r].x += a.x*b0.x + a.y*b1.x + a.z*b2.x + a.w*b3.x;
            acc[r].y += a.x*b0.y + a.y*b1.y + a.z*b2.y + a.w*b3.y;
            acc[r].z += a.x*b0.z + a.y*b1.z + a.z*b2.z + a.w*b3.z;
            acc[r].w += a.x*b0.w + a.y*b1.w + a.z*b2.w + a.w*b3.w;
        }
    }
    float4 bb = *(const float4*)(Bi + cq);
    #pragma unroll
    for (int r = 0; r < 8; ++r) {
        ushort4 o;
        o.x = f2bf((acc[r].x + bb.x)*sc);
        o.y = f2bf((acc[r].y + bb.y)*sc);
        o.z = f2bf((acc[r].z + bb.z)*sc);
        o.w = f2bf((acc[r].w + bb.w)*sc);
        *(ushort4*)(O + (size_t)(m0 + rg + r)*256 + cq) = o;
    }
}

// ---------------------------------------------------------------- V transpose per (bp,h)
__global__ __launch_bounds__(256) void vtrans(
    const ushort* __restrict__ vab, ushort* __restrict__ vt)
{
    __shared__ ushort L[192*36];
    int bph = blockIdx.x;            // bp*8 + h
    int bp = bph >> 3, h = bph & 7;
    int t = threadIdx.x;
    #pragma unroll
    for (int i = 0; i < 6; ++i) {
        int idx = i*256 + t;         // 1536 ushort4 total
        int pos = idx >> 3, c4 = (idx & 7)*4;
        ushort4 v = *(const ushort4*)(vab + ((size_t)(bp*192 + pos))*256 + h*32 + c4);
        *(ushort4*)(L + pos*36 + c4) = v;
    }
    __syncthreads();
    int dk = t >> 3, seg = t & 7;
    size_t ob = ((size_t)bph*32 + dk)*192 + seg*24;
    #pragma unroll
    for (int j = 0; j < 6; ++j) {
        int p0 = seg*24 + j*4;
        ushort4 o;
        o.x = L[(p0+0)*36 + dk];
        o.y = L[(p0+1)*36 + dk];
        o.z = L[(p0+2)*36 + dk];
        o.w = L[(p0+3)*36 + dk];
        *(ushort4*)(vt + ob + j*4) = o;
    }
}

// ---------------------------------------------------------------- MFMA flash attention
__global__ __launch_bounds__(256) void attn_mfma(
    const ushort* __restrict__ qab, const ushort* __restrict__ kab,
    const ushort* __restrict__ vt, const int* __restrict__ Rix,
    float* __restrict__ pl, float* __restrict__ pacc)
{
    __shared__ ushort P[4][16*40];    // per-wave P tile, stride 40 shorts
    int tid = threadIdx.x, w = tid >> 6, lane = tid & 63;
    int lm = lane & 15, lq = lane >> 4;
    int bph = blockIdx.x, kvb = blockIdx.y;
    int bp = bph >> 3, h = bph & 7, b = bp >> 3;
    int r = Rix[bp*4 + kvb];

    bf16x8 qf[3];
    #pragma unroll
    for (int t = 0; t < 3; ++t)
        qf[t] = *(const bf16x8*)(qab + ((size_t)(bp*192 + w*48 + t*16 + lm))*256 + h*32 + lq*8);

    const ushort* kbase = kab + ((size_t)((b*8 + r)*192))*256 + h*32 + lq*8;
    const ushort* vbase = vt + ((size_t)((b*8 + r)*8 + h))*32*192 + lq*8;
    ushort* pw = P[w];

    f32x4 O[3][2];
    #pragma unroll
    for (int t = 0; t < 3; ++t) { O[t][0] = (f32x4){0,0,0,0}; O[t][1] = (f32x4){0,0,0,0}; }
    float l[3] = {0.f, 0.f, 0.f};

    for (int k0 = 0; k0 < 192; k0 += 32) {
        bf16x8 kf0 = *(const bf16x8*)(kbase + (size_t)(k0 + lm)*256);
        bf16x8 kf1 = *(const bf16x8*)(kbase + (size_t)(k0 + 16 + lm)*256);
        bf16x8 vf0 = *(const bf16x8*)(vbase + (size_t)(lm)*192 + k0);        // dk 0..15
        bf16x8 vf1 = *(const bf16x8*)(vbase + (size_t)(16 + lm)*192 + k0);   // dk 16..31
        #pragma unroll
        for (int t = 0; t < 3; ++t) {
            f32x4 s0 = __builtin_amdgcn_mfma_f32_16x16x32_bf16(kf0, qf[t], (f32x4){0,0,0,0}, 0,0,0);
            f32x4 s1 = __builtin_amdgcn_mfma_f32_16x16x32_bf16(kf1, qf[t], (f32x4){0,0,0,0}, 0,0,0);
            float p0[4], p1[4];
            #pragma unroll
            for (int j = 0; j < 4; ++j) { p0[j] = __expf(s0[j]); p1[j] = __expf(s1[j]); }
            l[t] += p0[0]+p0[1]+p0[2]+p0[3] + p1[0]+p1[1]+p1[2]+p1[3];
            ushort4 a, c;
            a.x = f2bf(p0[0]); a.y = f2bf(p0[1]); a.z = f2bf(p0[2]); a.w = f2bf(p0[3]);
            c.x = f2bf(p1[0]); c.y = f2bf(p1[1]); c.z = f2bf(p1[2]); c.w = f2bf(p1[3]);
            *(ushort4*)(pw + lm*40 + lq*4)      = a;
            *(ushort4*)(pw + lm*40 + 16 + lq*4) = c;
            bf16x8 pf = *(const bf16x8*)(pw + lm*40 + lq*8);
            O[t][0] = __builtin_amdgcn_mfma_f32_16x16x32_bf16(pf, vf0, O[t][0], 0,0,0);
            O[t][1] = __builtin_amdgcn_mfma_f32_16x16x32_bf16(pf, vf1, O[t][1], 0,0,0);
        }
    }

    #pragma unroll
    for (int t = 0; t < 3; ++t) {
        float lt = l[t];
        lt += __shfl_xor(lt, 16);
        lt += __shfl_xor(lt, 32);
        size_t pbase = ((size_t)(bph*4 + kvb))*192 + w*48 + t*16;
        if (lq == 0) pl[pbase + lm] = lt;
        #pragma unroll
        for (int nt = 0; nt < 2; ++nt)
            #pragma unroll
            for (int reg = 0; reg < 4; ++reg)
                pacc[(pbase + lq*4 + reg)*32 + nt*16 + lm] = O[t][nt][reg];
    }
}

// ---------------------------------------------------------------- merge kv-partials -> ctx
__global__ __launch_bounds__(256) void attn_merge2(
    const float* __restrict__ pl, const float* __restrict__ pacc, float* __restrict__ ctx)
{
    int idx = blockIdx.x*256 + threadIdx.x;
    int d  = idx & 31;
    int gq = idx >> 5;
    int bph = gq / 192;
    int q = gq - bph*192;
    int bp = bph >> 3, h = bph & 7;
    float ls = 0.f, cv = 0.f;
    #pragma unroll
    for (int k = 0; k < 4; ++k) {
        size_t p = ((size_t)(bph*4 + k))*192 + q;
        ls += pl[p];
        cv += pacc[p*32 + d];
    }
    ctx[((size_t)(bp*192 + q))*256 + h*32 + d] = cv / ls;
}

// ---------------------------------------------------------------- padded bf16 conv input
__global__ __launch_bounds__(256) void addkv_pad(
    const float* __restrict__ kp, const float* __restrict__ vp, ushort* __restrict__ kvb)
{
    int t  = blockIdx.x*256 + threadIdx.x;
    int ci = (t & 63) * 4;
    int p  = t >> 6;
    int xp = p % 28;
    int rr = p / 28;
    int yp = rr % 68;
    int b  = rr / 68;
    int y = yp - 2, x = xp - 2;
    float4 s = make_float4(0.f,0.f,0.f,0.f);
    if (y >= 0 && y < 64 && x >= 0 && x < 24) {
        size_t base = ((size_t)((b*64 + y)*24 + x))*256 + ci;
        float4 a = *(const float4*)(kp + base);
        float4 c = *(const float4*)(vp + base);
        s.x = a.x + c.x; s.y = a.y + c.y; s.z = a.z + c.z; s.w = a.w + c.w;
    }
    ushort4 o;
    o.x = f2bf(s.x); o.y = f2bf(s.y); o.z = f2bf(s.z); o.w = f2bf(s.w);
    *(ushort4*)(kvb + (size_t)p*256 + ci) = o;
}

// ---------------------------------------------------------------- conv weight transpose
__global__ __launch_bounds__(256) void wtrans(
    const float* __restrict__ cw, ushort* __restrict__ wct)
{
    __shared__ float l[64*65];
    int blk = blockIdx.x;
    int tap = blk >> 4;
    int r2  = blk & 15;
    int ci0 = (r2 >> 2) * 64;
    int co0 = (r2 & 3) * 64;
    int tid = threadIdx.x;
    int a = tid >> 6;
    int c = tid & 63;
    #pragma unroll 4
    for (int k = 0; k < 16; ++k) {
        int cil = k*4 + a;
        l[cil*65 + c] = cw[(size_t)tap*65536 + (size_t)(ci0 + cil)*256 + co0 + c];
    }
    __syncthreads();
    #pragma unroll 4
    for (int k = 0; k < 16; ++k) {
        int col = k*4 + a;
        wct[((size_t)(tap*256 + co0 + col))*256 + ci0 + c] = f2bf(l[c*65 + col]);
    }
}

// ---------------------------------------------------------------- implicit-GEMM conv v2
// Block = (row-pair rp, dy): 64*5 = 320 blocks, 4 waves = 4 co-quarters.
// Two padded image rows staged in LDS (shared by all waves); B register-prefetched.
// Per (dx,ch) iteration per wave: 4 ds_read A-frags, 4 global B-frags, 16 MFMAs.
__global__ __launch_bounds__(256) void conv_mfma2(
    const ushort* __restrict__ kvb, const ushort* __restrict__ wct,
    float* __restrict__ pconv)
{
    __shared__ __align__(16) ushort Arows[2][9216];  // 28 pos + 8 pos overrun pad, x256 ci
    int tid = threadIdx.x;
    int bid = blockIdx.x;                 // rp*5 + dy
    int rp = bid / 5, dy = bid - rp*5;
    int b = rp >> 5, y0 = (rp & 31)*2;

    // stage 2 padded rows (each 28*256 = 7168 ushorts, contiguous in kvb)
    const ushort* src0 = kvb + ((size_t)((b*68 + y0 + dy)*28))*256;
    const ushort* src1 = kvb + ((size_t)((b*68 + y0 + 1 + dy)*28))*256;
    #pragma unroll
    for (int i = 0; i < 7; ++i) {
        int c = i*256 + tid;              // 0..1791 ushort8-chunks
        int row = (c >= 896);
        int off = (c - row*896) * 8;
        *(bf16x8*)(&Arows[row][off]) = *(const bf16x8*)((row ? src1 : src0) + off);
    }
    __syncthreads();

    int w = tid >> 6;                     // co quarter
    int lane = tid & 63, lm = lane & 15, lq = lane >> 4;
    const ushort* bbase = wct + ((size_t)((dy*5)*256 + w*64 + lm))*256 + lq*8;
    const ushort* a00 = &Arows[0][lm*256 + lq*8];

    f32x4 acc[2][2][4];
    #pragma unroll
    for (int r = 0; r < 2; ++r)
        #pragma unroll
        for (int mt = 0; mt < 2; ++mt)
            #pragma unroll
            for (int nt = 0; nt < 4; ++nt)
                acc[r][mt][nt] = (f32x4){0.f,0.f,0.f,0.f};

    bf16x8 bw[4];
    #pragma unroll
    for (int nt = 0; nt < 4; ++nt) bw[nt] = *(const bf16x8*)(bbase + nt*4096);

    for (int iter = 0; iter < 40; ++iter) {          // iter = dx*8 + ch
        int nx = (iter + 1 < 40) ? iter + 1 : 39;
        int boff = (nx >> 3)*65536 + (nx & 7)*32;
        bf16x8 bn[4];
        #pragma unroll
        for (int nt = 0; nt < 4; ++nt) bn[nt] = *(const bf16x8*)(bbase + boff + nt*4096);

        int aoff = (iter >> 3)*256 + (iter & 7)*32;  // dx*256 + ch*32
        bf16x8 af[2][2];
        #pragma unroll
        for (int r = 0; r < 2; ++r)
            #pragma unroll
            for (int mt = 0; mt < 2; ++mt)
                af[r][mt] = *(const bf16x8*)(a00 + r*9216 + mt*4096 + aoff);

        #pragma unroll
        for (int r = 0; r < 2; ++r)
            #pragma unroll
            for (int mt = 0; mt < 2; ++mt)
                #pragma unroll
                for (int nt = 0; nt < 4; ++nt)
                    acc[r][mt][nt] = __builtin_amdgcn_mfma_f32_16x16x32_bf16(
                        af[r][mt], bw[nt], acc[r][mt][nt], 0, 0, 0);

        #pragma unroll
        for (int nt = 0; nt < 4; ++nt) bw[nt] = bn[nt];
    }

    // store: D col=lm -> co sub-index, row=lq*4+j -> x position
    #pragma unroll
    for (int r = 0; r < 2; ++r) {
        int grow = rp*2 + r;                         // b*64 + y
        #pragma unroll
        for (int mt = 0; mt < 2; ++mt) {
            #pragma unroll
            for (int nt = 0; nt < 4; ++nt) {
                #pragma unroll
                for (int j = 0; j < 4; ++j) {
                    int x = mt*16 + lq*4 + j;
                    if (x < 24)
                        pconv[((size_t)(dy*3072 + grow*24 + x))*256 + w*64 + nt*16 + lm]
                            = acc[r][mt][nt][j];
                }
            }
        }
    }
}

// ---------------------------------------------------------------- sum 5 dy-partials + bias
__global__ __launch_bounds__(256) void reduce5(
    const float* __restrict__ pc, const float* __restrict__ cb, float* __restrict__ g)
{
    int i  = (blockIdx.x*256 + threadIdx.x)*4;
    int co = i & 255;
    float4 s = *(const float4*)(cb + co);
    #pragma unroll
    for (int d = 0; d < 5; ++d) {
        float4 v = *(const float4*)(pc + (size_t)d*NE + i);
        s.x += v.x; s.y += v.y; s.z += v.z; s.w += v.w;
    }
    *(float4*)(g + i) = s;
}

// ---------------------------------------------------------------- block descriptors
__global__ __launch_bounds__(256) void locmean(
    const float* __restrict__ qp, const float* __restrict__ kp,
    float* __restrict__ qloc, float* __restrict__ kloc)
{
    int bp = blockIdx.x;
    int c  = threadIdx.x;
    const float* src = blockIdx.y ? kp : qp;
    float*       dst = blockIdx.y ? kloc : qloc;
    float s = 0.f;
    for (int i = 0; i < 192; ++i)
        s += src[((size_t)(bp*192 + i))*256 + c];
    dst[bp*256 + c] = s * (1.0f/192.0f);
}

// ---------------------------------------------------------------- routing top-k
__global__ void topk_kern(const float* __restrict__ qloc, const float* __restrict__ kloc,
                          int* __restrict__ Rix)
{
    __shared__ float S[64];
    int b = blockIdx.x, t = threadIdx.x;
    int p = t >> 3, qq = t & 7;
    float s = 0.f;
    for (int c = 0; c < 256; ++c)
        s += qloc[(b*8+p)*256 + c] * kloc[(b*8+qq)*256 + c];
    S[t] = s;
    __syncthreads();
    if (t < 8) {
        float vals[8];
        #pragma unroll
        for (int j = 0; j < 8; ++j) vals[j] = S[t*8 + j];
        for (int j = 0; j < 4; ++j) {
            int best = 0; float bv = vals[0];
            #pragma unroll
            for (int i = 1; i < 8; ++i) if (vals[i] > bv) { bv = vals[i]; best = i; }
            Rix[(b*8 + t)*4 + j] = best;
            vals[best] = -1e30f;
        }
    }
}

// ---------------------------------------------------------------- residual + LayerNorm
__global__ __launch_bounds__(256) void ln_add(
    const float* __restrict__ A, const float* __restrict__ B1,
    const float* __restrict__ gamma, const float* __restrict__ beta,
    float* __restrict__ out)
{
    int pos  = blockIdx.x*4 + (threadIdx.x >> 6);
    int lane = threadIdx.x & 63;
    size_t base = (size_t)pos*256 + lane*4;
    float4 a = *(const float4*)(A + base);
    float4 b = *(const float4*)(B1 + base);
    float x0 = a.x + b.x, x1 = a.y + b.y, x2 = a.z + b.z, x3 = a.w + b.w;
    float s  = x0 + x1 + x2 + x3;
    float sq = x0*x0 + x1*x1 + x2*x2 + x3*x3;
    #pragma unroll
    for (int off = 32; off > 0; off >>= 1) {
        s  += __shfl_xor(s,  off);
        sq += __shfl_xor(sq, off);
    }
    float mean = s * (1.0f/256.0f);
    float var  = sq * (1.0f/256.0f) - mean*mean;
    float rstd = rsqrtf(var + 1e-5f);
    float4 gv = *(const float4*)(gamma + lane*4);
    float4 bv = *(const float4*)(beta  + lane*4);
    float4 o;
    o.x = (x0 - mean)*rstd*gv.x + bv.x;
    o.y = (x1 - mean)*rstd*gv.y + bv.y;
    o.z = (x2 - mean)*rstd*gv.z + bv.z;
    o.w = (x3 - mean)*rstd*gv.w + bv.w;
    *(float4*)(out + base) = o;
}

// ---------------------------------------------------------------- launcher
extern "C" void kernel_launch(void* const* d_in, const int* in_sizes, int n_in,
                              void* d_out, int out_size, void* d_ws, size_t ws_size,
                              hipStream_t stream)
{
    (void)in_sizes; (void)n_in; (void)out_size; (void)ws_size;
    const float* x    = (const float*)d_in[0];
    const float* wq   = (const float*)d_in[1];
    const float* bq   = (const float*)d_in[2];
    const float* wk   = (const float*)d_in[3];
    const float* bk   = (const float*)d_in[4];
    const float* wv   = (const float*)d_in[5];
    const float* bv   = (const float*)d_in[6];
    const float* wqa  = (const float*)d_in[7];
    const float* bqa  = (const float*)d_in[8];
    const float* wka  = (const float*)d_in[9];
    const float* bka  = (const float*)d_in[10];
    const float* wva  = (const float*)d_in[11];
    const float* bva  = (const float*)d_in[12];
    const float* woa  = (const float*)d_in[13];
    const float* boa  = (const float*)d_in[14];
    const float* cw   = (const float*)d_in[15];
    const float* cbi  = (const float*)d_in[16];
    const float* ln1g = (const float*)d_in[17];
    const float* ln1b = (const float*)d_in[18];
    const float* ln2g = (const float*)d_in[19];
    const float* ln2b = (const float*)d_in[20];
    float* out = (float*)d_out;

    float* ws = (float*)d_ws;
    float* q_p  = ws + 0ull*NE;
    float* k_p  = ws + 1ull*NE;
    float* v_p  = ws + 2ull*NE;
    ushort* qab = (ushort*)(ws + 3ull*NE);
    ushort* kab = qab + NE;
    ushort* vab = (ushort*)(ws + 4ull*NE);
    ushort* vt  = (ushort*)(ws + 4ull*NE + NE/2);
    float* pacc = ws + 5ull*NE;
    ushort* kvb = (ushort*)(ws + 10ull*NE);
    ushort* wct = (ushort*)(ws + 10ull*NE + 487424);
    float* qloc = ws + 10ull*NE + 487424 + 819200;
    float* kloc = qloc + 4096;
    int*   Rix  = (int*)(kloc + 4096);
    // aliases (stream-ordered disjoint lifetimes):
    float* routing = q_p;
    float* x_res   = k_p;
    float* g       = v_p;
    float* ctx     = (float*)qab;        // qab+kab dead after attn
    float* pl      = (float*)vab;        // vab dead after vtrans
    float* pconv   = pacc;               // pacc dead after merge

    // 1. q/k/v projections (fp32 — routing top-k needs exact scores)
    gemm_k3<<<dim3(96,3), 256, 0, stream>>>(x,x,x, wq,wk,wv, bq,bk,bv, q_p,k_p,v_p);
    // 2-3. conv input + weights (bf16)
    addkv_pad<<<952, 256, 0, stream>>>(k_p, v_p, kvb);
    wtrans<<<400, 256, 0, stream>>>(cw, wct);
    // 4-5. routing
    locmean<<<dim3(16,2), 256, 0, stream>>>(q_p, k_p, qloc, kloc);
    topk_kern<<<2, 64, 0, stream>>>(qloc, kloc, Rix);
    // 6. attention projections -> bf16 (qab pre-scaled by 1/sqrt(dk))
    gemm_k3b<<<dim3(96,3), 256, 0, stream>>>(q_p,k_p,v_p, wqa,wka,wva, bqa,bka,bva, qab,kab,vab);
    // 7. V transpose
    vtrans<<<128, 256, 0, stream>>>(vab, vt);
    // 8. MFMA flash attention
    attn_mfma<<<dim3(128,4), 256, 0, stream>>>(qab, kab, vt, Rix, pl, pacc);
    // 9. merge -> ctx
    attn_merge2<<<NE/256, 256, 0, stream>>>(pl, pacc, ctx);
    // 10. output projection
    gemm_k3<<<dim3(96,1), 256, 0, stream>>>(ctx,ctx,ctx, woa,woa,woa, boa,boa,boa,
                                            routing,routing,routing);
    // 11. LN1(x + routing)
    ln_add<<<NPOS/4, 256, 0, stream>>>(x, routing, ln1g, ln1b, x_res);
    // 12-13. conv v2 (LDS-shared A, register-prefetched B) + reduce
    conv_mfma2<<<320, 256, 0, stream>>>(kvb, wct, pconv);
    reduce5<<<768, 256, 0, stream>>>(pconv, cbi, g);
    // 14. LN2(x_res + g) -> out
    ln_add<<<NPOS/4, 256, 0, stream>>>(x_res, g, ln2g, ln2b, out);
}

// Round 6
// 230.840 us; speedup vs baseline: 2.9973x; 1.1941x over previous
//
#include <hip/hip_runtime.h>
#include <hip/hip_bf16.h>

// DRSA temporal block. B=2, P=8, hp=8, W=24, C=256, NH=8, dk=32, kv=4, H=64.
// 3072 positions, [pos][256] row-major. All GEMM-shaped work on bf16 MFMA;
// routing descriptors in exact fp32 via mean-commutes-with-projection.

#define NPOS 3072
#define CD   256
#define NE   (NPOS*CD)

typedef short bf16x8 __attribute__((ext_vector_type(8)));
typedef float f32x4  __attribute__((ext_vector_type(4)));

__device__ inline ushort f2bf(float f) {
    __hip_bfloat16 h = __float2bfloat16(f);   // RNE
    return *reinterpret_cast<ushort*>(&h);
}
__device__ inline float bf2f(ushort u) {
    unsigned v = ((unsigned)u) << 16;
    return *reinterpret_cast<float*>(&v);
}

// ---------------------------------------------------------------- x -> bf16
__global__ __launch_bounds__(256) void castx(
    const float* __restrict__ x, ushort* __restrict__ xb)
{
    int i = (blockIdx.x*256 + threadIdx.x)*4;
    float4 v = *(const float4*)(x + i);
    ushort4 o;
    o.x = f2bf(v.x); o.y = f2bf(v.y); o.z = f2bf(v.z); o.w = f2bf(v.w);
    *(ushort4*)(xb + i) = o;
}

// ---------------------------------------------------------------- 7 weight transposes -> bf16
// W [k][n] fp32 -> wt7[mat][n][k] bf16 (k-contiguous B operand).
__global__ __launch_bounds__(256) void wtrans7(
    const float* __restrict__ w0, const float* __restrict__ w1, const float* __restrict__ w2,
    const float* __restrict__ w3, const float* __restrict__ w4, const float* __restrict__ w5,
    const float* __restrict__ w6, ushort* __restrict__ wt)
{
    __shared__ float l[64*65];
    int mat = blockIdx.y;
    const float* Wm = mat==0?w0:mat==1?w1:mat==2?w2:mat==3?w3:mat==4?w4:mat==5?w5:w6;
    int r2 = blockIdx.x;
    int ci0 = (r2 >> 2)*64, co0 = (r2 & 3)*64;
    int tid = threadIdx.x, a = tid >> 6, c = tid & 63;
    #pragma unroll 4
    for (int k = 0; k < 16; ++k) {
        int cil = k*4 + a;
        l[cil*65 + c] = Wm[(size_t)(ci0 + cil)*256 + co0 + c];
    }
    __syncthreads();
    #pragma unroll 4
    for (int k = 0; k < 16; ++k) {
        int col = k*4 + a;
        wt[(size_t)mat*65536 + ((size_t)(co0 + col))*256 + ci0 + c] = f2bf(l[c*65 + col]);
    }
}

// ---------------------------------------------------------------- conv weight transpose
__global__ __launch_bounds__(256) void wtrans(
    const float* __restrict__ cw, ushort* __restrict__ wct)
{
    __shared__ float l[64*65];
    int blk = blockIdx.x;
    int tap = blk >> 4;
    int r2  = blk & 15;
    int ci0 = (r2 >> 2) * 64;
    int co0 = (r2 & 3) * 64;
    int tid = threadIdx.x;
    int a = tid >> 6;
    int c = tid & 63;
    #pragma unroll 4
    for (int k = 0; k < 16; ++k) {
        int cil = k*4 + a;
        l[cil*65 + c] = cw[(size_t)tap*65536 + (size_t)(ci0 + cil)*256 + co0 + c];
    }
    __syncthreads();
    #pragma unroll 4
    for (int k = 0; k < 16; ++k) {
        int col = k*4 + a;
        wct[((size_t)(tap*256 + co0 + col))*256 + ci0 + c] = f2bf(l[c*65 + col]);
    }
}

// ---------------------------------------------------------------- mean of x per (b,p) [fp32 exact]
__global__ __launch_bounds__(256) void xmean(
    const float* __restrict__ x, float* __restrict__ xloc)
{
    int bp = blockIdx.x, c = threadIdx.x;
    float s = 0.f;
    for (int i = 0; i < 192; ++i)
        s += x[((size_t)(bp*192 + i))*256 + c];
    xloc[bp*256 + c] = s * (1.0f/192.0f);
}

// ---------------------------------------------------------------- q_loc/k_loc = xloc@W + b [fp32]
__global__ __launch_bounds__(256) void qkloc_kern(
    const float* __restrict__ xloc,
    const float* __restrict__ wq, const float* __restrict__ bq,
    const float* __restrict__ wk, const float* __restrict__ bk,
    float* __restrict__ qloc, float* __restrict__ kloc)
{
    __shared__ float xs[256];
    int bp = blockIdx.x, c = threadIdx.x;
    const float* W  = blockIdx.y ? wk : wq;
    const float* Bv = blockIdx.y ? bk : bq;
    float* dst      = blockIdx.y ? kloc : qloc;
    xs[c] = xloc[bp*256 + c];
    __syncthreads();
    float s = Bv[c];
    #pragma unroll 8
    for (int k = 0; k < 256; ++k)
        s += xs[k] * W[(size_t)k*256 + c];
    dst[bp*256 + c] = s;
}

// ---------------------------------------------------------------- routing top-k (fp32 exact)
__global__ void topk_kern(const float* __restrict__ qloc, const float* __restrict__ kloc,
                          int* __restrict__ Rix)
{
    __shared__ float S[64];
    int b = blockIdx.x, t = threadIdx.x;
    int p = t >> 3, qq = t & 7;
    float s = 0.f;
    for (int c = 0; c < 256; ++c)
        s += qloc[(b*8+p)*256 + c] * kloc[(b*8+qq)*256 + c];
    S[t] = s;
    __syncthreads();
    if (t < 8) {
        float vals[8];
        #pragma unroll
        for (int j = 0; j < 8; ++j) vals[j] = S[t*8 + j];
        for (int j = 0; j < 4; ++j) {
            int best = 0; float bv = vals[0];
            #pragma unroll
            for (int i = 1; i < 8; ++i) if (vals[i] > bv) { bv = vals[i]; best = i; }
            Rix[(b*8 + t)*4 + j] = best;
            vals[best] = -1e30f;
        }
    }
}

// ---------------------------------------------------------------- bf16 MFMA GEMM triple
// O = A(bf16 [3072][256]) @ WtT(bf16 [n][k]) + bias. Out bf16 (scaled) or fp32 (F != null).
// 32-row tiles, 4 waves = 4 n-slices of 64. A staged in LDS stride 264 (conflict-min).
__global__ __launch_bounds__(256) void gemm_bt3(
    const ushort* __restrict__ A0, const ushort* __restrict__ A1, const ushort* __restrict__ A2,
    const ushort* __restrict__ T0, const ushort* __restrict__ T1, const ushort* __restrict__ T2,
    const float* __restrict__ B0, const float* __restrict__ B1, const float* __restrict__ B2,
    ushort* __restrict__ U0, ushort* __restrict__ U1, ushort* __restrict__ U2,
    float* __restrict__ F0, float* __restrict__ F1, float* __restrict__ F2,
    float s0, float s1, float s2)
{
    __shared__ __align__(16) ushort As[32*264];
    int y = blockIdx.y;
    const ushort* A = y==0 ? A0 : (y==1 ? A1 : A2);
    const ushort* T = y==0 ? T0 : (y==1 ? T1 : T2);
    const float* Bi = y==0 ? B0 : (y==1 ? B1 : B2);
    ushort* U = y==0 ? U0 : (y==1 ? U1 : U2);
    float*  F = y==0 ? F0 : (y==1 ? F1 : F2);
    float  sc = y==0 ? s0 : (y==1 ? s1 : s2);
    int tid = threadIdx.x;
    int m0 = blockIdx.x*32;
    #pragma unroll
    for (int i = 0; i < 4; ++i) {
        int c = i*256 + tid;                 // 1024 chunks of 8 ushorts
        int pos = c >> 5, off = (c & 31)*8;
        *(bf16x8*)&As[pos*264 + off] = *(const bf16x8*)(A + (size_t)(m0 + pos)*256 + off);
    }
    __syncthreads();
    int w = tid >> 6, lane = tid & 63, lm = lane & 15, lq = lane >> 4;
    const ushort* tb = T + ((size_t)(w*64 + lm))*256 + lq*8;

    f32x4 acc[2][4];
    #pragma unroll
    for (int mt = 0; mt < 2; ++mt)
        #pragma unroll
        for (int nt = 0; nt < 4; ++nt) acc[mt][nt] = (f32x4){0.f,0.f,0.f,0.f};

    bf16x8 bw[4];
    #pragma unroll
    for (int nt = 0; nt < 4; ++nt) bw[nt] = *(const bf16x8*)(tb + nt*4096);

    for (int kc = 0; kc < 8; ++kc) {
        int nk = (kc + 1 < 8) ? kc + 1 : 7;
        bf16x8 bn[4];
        #pragma unroll
        for (int nt = 0; nt < 4; ++nt) bn[nt] = *(const bf16x8*)(tb + nt*4096 + nk*32);
        bf16x8 af[2];
        #pragma unroll
        for (int mt = 0; mt < 2; ++mt)
            af[mt] = *(const bf16x8*)&As[(mt*16 + lm)*264 + kc*32 + lq*8];
        #pragma unroll
        for (int mt = 0; mt < 2; ++mt)
            #pragma unroll
            for (int nt = 0; nt < 4; ++nt)
                acc[mt][nt] = __builtin_amdgcn_mfma_f32_16x16x32_bf16(af[mt], bw[nt], acc[mt][nt], 0,0,0);
        #pragma unroll
        for (int nt = 0; nt < 4; ++nt) bw[nt] = bn[nt];
    }

    // D: col=lm -> n sub-index, row=lq*4+j -> m
    #pragma unroll
    for (int mt = 0; mt < 2; ++mt) {
        #pragma unroll
        for (int nt = 0; nt < 4; ++nt) {
            int n = w*64 + nt*16 + lm;
            float bb = Bi[n];
            #pragma unroll
            for (int j = 0; j < 4; ++j) {
                int m = m0 + mt*16 + lq*4 + j;
                float val = (acc[mt][nt][j] + bb) * sc;
                if (F) F[(size_t)m*256 + n] = val;
                else   U[(size_t)m*256 + n] = f2bf(val);
            }
        }
    }
}

// ---------------------------------------------------------------- V transpose per (bp,h)
__global__ __launch_bounds__(256) void vtrans(
    const ushort* __restrict__ vab, ushort* __restrict__ vt)
{
    __shared__ ushort L[192*36];
    int bph = blockIdx.x;
    int bp = bph >> 3, h = bph & 7;
    int t = threadIdx.x;
    #pragma unroll
    for (int i = 0; i < 6; ++i) {
        int idx = i*256 + t;
        int pos = idx >> 3, c4 = (idx & 7)*4;
        ushort4 v = *(const ushort4*)(vab + ((size_t)(bp*192 + pos))*256 + h*32 + c4);
        *(ushort4*)(L + pos*36 + c4) = v;
    }
    __syncthreads();
    int dk = t >> 3, seg = t & 7;
    size_t ob = ((size_t)bph*32 + dk)*192 + seg*24;
    #pragma unroll
    for (int j = 0; j < 6; ++j) {
        int p0 = seg*24 + j*4;
        ushort4 o;
        o.x = L[(p0+0)*36 + dk];
        o.y = L[(p0+1)*36 + dk];
        o.z = L[(p0+2)*36 + dk];
        o.w = L[(p0+3)*36 + dk];
        *(ushort4*)(vt + ob + j*4) = o;
    }
}

// ---------------------------------------------------------------- MFMA flash attention
__global__ __launch_bounds__(256) void attn_mfma(
    const ushort* __restrict__ qab, const ushort* __restrict__ kab,
    const ushort* __restrict__ vt, const int* __restrict__ Rix,
    float* __restrict__ pl, float* __restrict__ pacc)
{
    __shared__ ushort P[4][16*40];
    int tid = threadIdx.x, w = tid >> 6, lane = tid & 63;
    int lm = lane & 15, lq = lane >> 4;
    int bph = blockIdx.x, kvb = blockIdx.y;
    int bp = bph >> 3, h = bph & 7, b = bp >> 3;
    int r = Rix[bp*4 + kvb];

    bf16x8 qf[3];
    #pragma unroll
    for (int t = 0; t < 3; ++t)
        qf[t] = *(const bf16x8*)(qab + ((size_t)(bp*192 + w*48 + t*16 + lm))*256 + h*32 + lq*8);

    const ushort* kbase = kab + ((size_t)((b*8 + r)*192))*256 + h*32 + lq*8;
    const ushort* vbase = vt + ((size_t)((b*8 + r)*8 + h))*32*192 + lq*8;
    ushort* pw = P[w];

    f32x4 O[3][2];
    #pragma unroll
    for (int t = 0; t < 3; ++t) { O[t][0] = (f32x4){0,0,0,0}; O[t][1] = (f32x4){0,0,0,0}; }
    float l[3] = {0.f, 0.f, 0.f};

    for (int k0 = 0; k0 < 192; k0 += 32) {
        bf16x8 kf0 = *(const bf16x8*)(kbase + (size_t)(k0 + lm)*256);
        bf16x8 kf1 = *(const bf16x8*)(kbase + (size_t)(k0 + 16 + lm)*256);
        bf16x8 vf0 = *(const bf16x8*)(vbase + (size_t)(lm)*192 + k0);
        bf16x8 vf1 = *(const bf16x8*)(vbase + (size_t)(16 + lm)*192 + k0);
        #pragma unroll
        for (int t = 0; t < 3; ++t) {
            f32x4 s0 = __builtin_amdgcn_mfma_f32_16x16x32_bf16(kf0, qf[t], (f32x4){0,0,0,0}, 0,0,0);
            f32x4 s1 = __builtin_amdgcn_mfma_f32_16x16x32_bf16(kf1, qf[t], (f32x4){0,0,0,0}, 0,0,0);
            float p0[4], p1[4];
            #pragma unroll
            for (int j = 0; j < 4; ++j) { p0[j] = __expf(s0[j]); p1[j] = __expf(s1[j]); }
            l[t] += p0[0]+p0[1]+p0[2]+p0[3] + p1[0]+p1[1]+p1[2]+p1[3];
            ushort4 a, c;
            a.x = f2bf(p0[0]); a.y = f2bf(p0[1]); a.z = f2bf(p0[2]); a.w = f2bf(p0[3]);
            c.x = f2bf(p1[0]); c.y = f2bf(p1[1]); c.z = f2bf(p1[2]); c.w = f2bf(p1[3]);
            *(ushort4*)(pw + lm*40 + lq*4)      = a;
            *(ushort4*)(pw + lm*40 + 16 + lq*4) = c;
            bf16x8 pf = *(const bf16x8*)(pw + lm*40 + lq*8);
            O[t][0] = __builtin_amdgcn_mfma_f32_16x16x32_bf16(pf, vf0, O[t][0], 0,0,0);
            O[t][1] = __builtin_amdgcn_mfma_f32_16x16x32_bf16(pf, vf1, O[t][1], 0,0,0);
        }
    }

    #pragma unroll
    for (int t = 0; t < 3; ++t) {
        float lt = l[t];
        lt += __shfl_xor(lt, 16);
        lt += __shfl_xor(lt, 32);
        size_t pbase = ((size_t)(bph*4 + kvb))*192 + w*48 + t*16;
        if (lq == 0) pl[pbase + lm] = lt;
        #pragma unroll
        for (int nt = 0; nt < 2; ++nt)
            #pragma unroll
            for (int reg = 0; reg < 4; ++reg)
                pacc[(pbase + lq*4 + reg)*32 + nt*16 + lm] = O[t][nt][reg];
    }
}

// ---------------------------------------------------------------- merge kv-partials -> ctx bf16
__global__ __launch_bounds__(256) void attn_merge2(
    const float* __restrict__ pl, const float* __restrict__ pacc, ushort* __restrict__ ctxb)
{
    int idx = blockIdx.x*256 + threadIdx.x;
    int d  = idx & 31;
    int gq = idx >> 5;
    int bph = gq / 192;
    int q = gq - bph*192;
    int bp = bph >> 3, h = bph & 7;
    float ls = 0.f, cv = 0.f;
    #pragma unroll
    for (int k = 0; k < 4; ++k) {
        size_t p = ((size_t)(bph*4 + k))*192 + q;
        ls += pl[p];
        cv += pacc[p*32 + d];
    }
    ctxb[((size_t)(bp*192 + q))*256 + h*32 + d] = f2bf(cv / ls);
}

// ---------------------------------------------------------------- padded bf16 conv input (bf16 in)
__global__ __launch_bounds__(256) void addkv_pad2(
    const ushort* __restrict__ kpb, const ushort* __restrict__ vpb, ushort* __restrict__ kvb)
{
    int t  = blockIdx.x*256 + threadIdx.x;
    int ci = (t & 63) * 4;
    int p  = t >> 6;
    int xp = p % 28;
    int rr = p / 28;
    int yp = rr % 68;
    int b  = rr / 68;
    int y = yp - 2, x = xp - 2;
    ushort4 o; o.x = 0; o.y = 0; o.z = 0; o.w = 0;
    if (y >= 0 && y < 64 && x >= 0 && x < 24) {
        size_t base = ((size_t)((b*64 + y)*24 + x))*256 + ci;
        ushort4 a = *(const ushort4*)(kpb + base);
        ushort4 c = *(const ushort4*)(vpb + base);
        o.x = f2bf(bf2f(a.x) + bf2f(c.x));
        o.y = f2bf(bf2f(a.y) + bf2f(c.y));
        o.z = f2bf(bf2f(a.z) + bf2f(c.z));
        o.w = f2bf(bf2f(a.w) + bf2f(c.w));
    }
    *(ushort4*)(kvb + (size_t)p*256 + ci) = o;
}

// ---------------------------------------------------------------- implicit-GEMM conv v3
// Same as v2 but LDS stride 264 ushorts (528 B): bank window rotates with position,
// ds_read_b128 at structural-minimum banking (was 16-way conflicted at stride 512 B).
__global__ __launch_bounds__(256) void conv_mfma2(
    const ushort* __restrict__ kvb, const ushort* __restrict__ wct,
    float* __restrict__ pconv)
{
    __shared__ __align__(16) ushort Arows[2][9504];  // 36 pos x 264 (28 real + 8 overrun)
    int tid = threadIdx.x;
    int bid = blockIdx.x;                 // rp*5 + dy
    int rp = bid / 5, dy = bid - rp*5;
    int b = rp >> 5, y0 = (rp & 31)*2;

    const ushort* src0 = kvb + ((size_t)((b*68 + y0 + dy)*28))*256;
    const ushort* src1 = kvb + ((size_t)((b*68 + y0 + 1 + dy)*28))*256;
    #pragma unroll
    for (int i = 0; i < 7; ++i) {
        int c = i*256 + tid;              // 1792 chunks of 8
        int row = (c >= 896);
        int cc = c - row*896;
        int pos = cc >> 5, off = (cc & 31)*8;
        *(bf16x8*)(&Arows[row][pos*264 + off]) =
            *(const bf16x8*)((row ? src1 : src0) + (size_t)(pos*256 + off));
    }
    __syncthreads();

    int w = tid >> 6;
    int lane = tid & 63, lm = lane & 15, lq = lane >> 4;
    const ushort* bbase = wct + ((size_t)((dy*5)*256 + w*64 + lm))*256 + lq*8;
    const ushort* a00 = &Arows[0][lm*264 + lq*8];

    f32x4 acc[2][2][4];
    #pragma unroll
    for (int r = 0; r < 2; ++r)
        #pragma unroll
        for (int mt = 0; mt < 2; ++mt)
            #pragma unroll
            for (int nt = 0; nt < 4; ++nt)
                acc[r][mt][nt] = (f32x4){0.f,0.f,0.f,0.f};

    bf16x8 bw[4];
    #pragma unroll
    for (int nt = 0; nt < 4; ++nt) bw[nt] = *(const bf16x8*)(bbase + nt*4096);

    for (int iter = 0; iter < 40; ++iter) {          // iter = dx*8 + ch
        int nx = (iter + 1 < 40) ? iter + 1 : 39;
        int boff = (nx >> 3)*65536 + (nx & 7)*32;
        bf16x8 bn[4];
        #pragma unroll
        for (int nt = 0; nt < 4; ++nt) bn[nt] = *(const bf16x8*)(bbase + boff + nt*4096);

        int aoff = (iter >> 3)*264 + (iter & 7)*32;  // dx*264 + ch*32
        bf16x8 af[2][2];
        #pragma unroll
        for (int r = 0; r < 2; ++r)
            #pragma unroll
            for (int mt = 0; mt < 2; ++mt)
                af[r][mt] = *(const bf16x8*)(a00 + r*9504 + mt*4224 + aoff);

        #pragma unroll
        for (int r = 0; r < 2; ++r)
            #pragma unroll
            for (int mt = 0; mt < 2; ++mt)
                #pragma unroll
                for (int nt = 0; nt < 4; ++nt)
                    acc[r][mt][nt] = __builtin_amdgcn_mfma_f32_16x16x32_bf16(
                        af[r][mt], bw[nt], acc[r][mt][nt], 0, 0, 0);

        #pragma unroll
        for (int nt = 0; nt < 4; ++nt) bw[nt] = bn[nt];
    }

    #pragma unroll
    for (int r = 0; r < 2; ++r) {
        int grow = rp*2 + r;
        #pragma unroll
        for (int mt = 0; mt < 2; ++mt) {
            #pragma unroll
            for (int nt = 0; nt < 4; ++nt) {
                #pragma unroll
                for (int j = 0; j < 4; ++j) {
                    int x = mt*16 + lq*4 + j;
                    if (x < 24)
                        pconv[((size_t)(dy*3072 + grow*24 + x))*256 + w*64 + nt*16 + lm]
                            = acc[r][mt][nt][j];
                }
            }
        }
    }
}

// ---------------------------------------------------------------- sum 5 dy-partials + bias
__global__ __launch_bounds__(256) void reduce5(
    const float* __restrict__ pc, const float* __restrict__ cb, float* __restrict__ g)
{
    int i  = (blockIdx.x*256 + threadIdx.x)*4;
    int co = i & 255;
    float4 s = *(const float4*)(cb + co);
    #pragma unroll
    for (int d = 0; d < 5; ++d) {
        float4 v = *(const float4*)(pc + (size_t)d*NE + i);
        s.x += v.x; s.y += v.y; s.z += v.z; s.w += v.w;
    }
    *(float4*)(g + i) = s;
}

// ---------------------------------------------------------------- residual + LayerNorm
__global__ __launch_bounds__(256) void ln_add(
    const float* __restrict__ A, const float* __restrict__ B1,
    const float* __restrict__ gamma, const float* __restrict__ beta,
    float* __restrict__ out)
{
    int pos  = blockIdx.x*4 + (threadIdx.x >> 6);
    int lane = threadIdx.x & 63;
    size_t base = (size_t)pos*256 + lane*4;
    float4 a = *(const float4*)(A + base);
    float4 b = *(const float4*)(B1 + base);
    float x0 = a.x + b.x, x1 = a.y + b.y, x2 = a.z + b.z, x3 = a.w + b.w;
    float s  = x0 + x1 + x2 + x3;
    float sq = x0*x0 + x1*x1 + x2*x2 + x3*x3;
    #pragma unroll
    for (int off = 32; off > 0; off >>= 1) {
        s  += __shfl_xor(s,  off);
        sq += __shfl_xor(sq, off);
    }
    float mean = s * (1.0f/256.0f);
    float var  = sq * (1.0f/256.0f) - mean*mean;
    float rstd = rsqrtf(var + 1e-5f);
    float4 gv = *(const float4*)(gamma + lane*4);
    float4 bv = *(const float4*)(beta  + lane*4);
    float4 o;
    o.x = (x0 - mean)*rstd*gv.x + bv.x;
    o.y = (x1 - mean)*rstd*gv.y + bv.y;
    o.z = (x2 - mean)*rstd*gv.z + bv.z;
    o.w = (x3 - mean)*rstd*gv.w + bv.w;
    *(float4*)(out + base) = o;
}

// ---------------------------------------------------------------- launcher
extern "C" void kernel_launch(void* const* d_in, const int* in_sizes, int n_in,
                              void* d_out, int out_size, void* d_ws, size_t ws_size,
                              hipStream_t stream)
{
    (void)in_sizes; (void)n_in; (void)out_size; (void)ws_size;
    const float* x    = (const float*)d_in[0];
    const float* wq   = (const float*)d_in[1];
    const float* bq   = (const float*)d_in[2];
    const float* wk   = (const float*)d_in[3];
    const float* bk   = (const float*)d_in[4];
    const float* wv   = (const float*)d_in[5];
    const float* bv   = (const float*)d_in[6];
    const float* wqa  = (const float*)d_in[7];
    const float* bqa  = (const float*)d_in[8];
    const float* wka  = (const float*)d_in[9];
    const float* bka  = (const float*)d_in[10];
    const float* wva  = (const float*)d_in[11];
    const float* bva  = (const float*)d_in[12];
    const float* woa  = (const float*)d_in[13];
    const float* boa  = (const float*)d_in[14];
    const float* cw   = (const float*)d_in[15];
    const float* cbi  = (const float*)d_in[16];
    const float* ln1g = (const float*)d_in[17];
    const float* ln1b = (const float*)d_in[18];
    const float* ln2g = (const float*)d_in[19];
    const float* ln2b = (const float*)d_in[20];
    float* out = (float*)d_out;

    // Workspace (float units), total ~8.63M floats = 34.5 MB (<36.7 proven):
    // [qpb ½][kpb ½][xb ½][vpb ½][qab ½][kab ½][vab ½][vt ½]  (8 bf16 half-slots)
    //   aliases: routing=qpb..kpb (NE f32), x_res=xb..vpb, g=qab..kab, ctxb=vab slot
    // R region: pacc(3145728)+pl(98304) -> pconv(3932160) after merge
    // wt7(229376) wct(819200) kvb(487424) xloc/qloc/kloc/Rix
    float* ws = (float*)d_ws;
    const size_t HNE = NE/2;
    ushort* qpb = (ushort*)(ws + 0*HNE);
    ushort* kpb = (ushort*)(ws + 1*HNE);
    ushort* xb  = (ushort*)(ws + 2*HNE);
    ushort* vpb = (ushort*)(ws + 3*HNE);
    ushort* qab = (ushort*)(ws + 4*HNE);
    ushort* kab = (ushort*)(ws + 5*HNE);
    ushort* vab = (ushort*)(ws + 6*HNE);
    ushort* vt  = (ushort*)(ws + 7*HNE);
    float* R    = ws + 8*HNE;            // 3,932,160 floats
    float* pacc = R;
    float* pl   = R + 3145728;
    float* pconv= R;
    ushort* wt7 = (ushort*)(R + 3932160);            // 458752 bf16 = 229376 f
    ushort* wct = (ushort*)(R + 3932160 + 229376);   // 1638400 bf16 = 819200 f
    ushort* kvb = (ushort*)(R + 3932160 + 229376 + 819200);  // 974848 bf16
    float* xloc = R + 3932160 + 229376 + 819200 + 487424;
    float* qloc = xloc + 4096;
    float* kloc = qloc + 4096;
    int*   Rix  = (int*)(kloc + 4096);
    // fp32 aliases over dead bf16 slots:
    float* routing = (float*)qpb;   // qpb+kpb dead after gemm2/addkv
    float* x_res   = (float*)xb;    // xb dead after gemm1; vpb dead after gemm2/addkv
    float* g       = (float*)qab;   // qab+kab dead after attn
    ushort* ctxb   = vab;           // vab dead after vtrans

    // 1. casts + weight preps
    castx<<<768, 256, 0, stream>>>(x, xb);
    wtrans7<<<dim3(16,7), 256, 0, stream>>>(wq,wk,wv,wqa,wka,wva,woa, wt7);
    wtrans<<<400, 256, 0, stream>>>(cw, wct);
    // 2. routing descriptors in exact fp32 (mean commutes with projection)
    xmean<<<16, 256, 0, stream>>>(x, xloc);
    qkloc_kern<<<dim3(16,2), 256, 0, stream>>>(xloc, wq,bq, wk,bk, qloc, kloc);
    topk_kern<<<2, 64, 0, stream>>>(qloc, kloc, Rix);
    // 3. q/k/v projections (bf16 MFMA)
    gemm_bt3<<<dim3(96,3), 256, 0, stream>>>(
        xb,xb,xb, wt7, wt7+65536, wt7+131072, bq,bk,bv,
        qpb,kpb,vpb, nullptr,nullptr,nullptr, 1.f,1.f,1.f);
    // 4. conv input (bf16)
    addkv_pad2<<<952, 256, 0, stream>>>(kpb, vpb, kvb);
    // 5. attention projections (qab pre-scaled by 1/sqrt(dk))
    gemm_bt3<<<dim3(96,3), 256, 0, stream>>>(
        qpb,kpb,vpb, wt7+196608, wt7+262144, wt7+327680, bqa,bka,bva,
        qab,kab,vab, nullptr,nullptr,nullptr, 0.17677669529663687f,1.f,1.f);
    // 6. V transpose, 7. MFMA flash attention, 8. merge -> ctx bf16
    vtrans<<<128, 256, 0, stream>>>(vab, vt);
    attn_mfma<<<dim3(128,4), 256, 0, stream>>>(qab, kab, vt, Rix, pl, pacc);
    attn_merge2<<<NE/256, 256, 0, stream>>>(pl, pacc, ctxb);
    // 9. output projection (bf16 MFMA -> fp32)
    gemm_bt3<<<dim3(96,1), 256, 0, stream>>>(
        ctxb,ctxb,ctxb, wt7+393216, wt7+393216, wt7+393216, boa,boa,boa,
        nullptr,nullptr,nullptr, routing,routing,routing, 1.f,1.f,1.f);
    // 10. LN1(x + routing)
    ln_add<<<NPOS/4, 256, 0, stream>>>(x, routing, ln1g, ln1b, x_res);
    // 11-12. conv v3 (conflict-free LDS) + reduce
    conv_mfma2<<<320, 256, 0, stream>>>(kvb, wct, pconv);
    reduce5<<<768, 256, 0, stream>>>(pconv, cbi, g);
    // 13. LN2(x_res + g) -> out
    ln_add<<<NPOS/4, 256, 0, stream>>>(x_res, g, ln2g, ln2b, out);
}

// Round 7
// 227.741 us; speedup vs baseline: 3.0381x; 1.0136x over previous
//
#include <hip/hip_runtime.h>
#include <hip/hip_bf16.h>

// DRSA temporal block. B=2, P=8, hp=8, W=24, C=256, NH=8, dk=32, kv=4, H=64.
// 3072 positions, [pos][256] row-major. All GEMM-shaped work on bf16 MFMA;
// routing descriptors in exact fp32 via mean-commutes-with-projection.

#define NPOS 3072
#define CD   256
#define NE   (NPOS*CD)

typedef short bf16x8 __attribute__((ext_vector_type(8)));
typedef float f32x4  __attribute__((ext_vector_type(4)));

__device__ inline ushort f2bf(float f) {
    __hip_bfloat16 h = __float2bfloat16(f);   // RNE
    return *reinterpret_cast<ushort*>(&h);
}
__device__ inline float bf2f(ushort u) {
    unsigned v = ((unsigned)u) << 16;
    return *reinterpret_cast<float*>(&v);
}

// ---------------------------------------------------------------- 7 weight transposes -> bf16
__global__ __launch_bounds__(256) void wtrans7(
    const float* __restrict__ w0, const float* __restrict__ w1, const float* __restrict__ w2,
    const float* __restrict__ w3, const float* __restrict__ w4, const float* __restrict__ w5,
    const float* __restrict__ w6, ushort* __restrict__ wt)
{
    __shared__ float l[64*65];
    int mat = blockIdx.y;
    const float* Wm = mat==0?w0:mat==1?w1:mat==2?w2:mat==3?w3:mat==4?w4:mat==5?w5:w6;
    int r2 = blockIdx.x;
    int ci0 = (r2 >> 2)*64, co0 = (r2 & 3)*64;
    int tid = threadIdx.x, a = tid >> 6, c = tid & 63;
    #pragma unroll 4
    for (int k = 0; k < 16; ++k) {
        int cil = k*4 + a;
        l[cil*65 + c] = Wm[(size_t)(ci0 + cil)*256 + co0 + c];
    }
    __syncthreads();
    #pragma unroll 4
    for (int k = 0; k < 16; ++k) {
        int col = k*4 + a;
        wt[(size_t)mat*65536 + ((size_t)(co0 + col))*256 + ci0 + c] = f2bf(l[c*65 + col]);
    }
}

// ---------------------------------------------------------------- conv weight transpose
__global__ __launch_bounds__(256) void wtrans(
    const float* __restrict__ cw, ushort* __restrict__ wct)
{
    __shared__ float l[64*65];
    int blk = blockIdx.x;
    int tap = blk >> 4;
    int r2  = blk & 15;
    int ci0 = (r2 >> 2) * 64;
    int co0 = (r2 & 3) * 64;
    int tid = threadIdx.x;
    int a = tid >> 6;
    int c = tid & 63;
    #pragma unroll 4
    for (int k = 0; k < 16; ++k) {
        int cil = k*4 + a;
        l[cil*65 + c] = cw[(size_t)tap*65536 + (size_t)(ci0 + cil)*256 + co0 + c];
    }
    __syncthreads();
    #pragma unroll 4
    for (int k = 0; k < 16; ++k) {
        int col = k*4 + a;
        wct[((size_t)(tap*256 + co0 + col))*256 + ci0 + c] = f2bf(l[c*65 + col]);
    }
}

// ---------------------------------------------------------------- mean of x per (b,p) [fp32 exact]
__global__ __launch_bounds__(256) void xmean(
    const float* __restrict__ x, float* __restrict__ xloc)
{
    int bp = blockIdx.x, c = threadIdx.x;
    float s = 0.f;
    for (int i = 0; i < 192; ++i)
        s += x[((size_t)(bp*192 + i))*256 + c];
    xloc[bp*256 + c] = s * (1.0f/192.0f);
}

// ---------------------------------------------------------------- q_loc/k_loc = xloc@W + b [fp32]
__global__ __launch_bounds__(256) void qkloc_kern(
    const float* __restrict__ xloc,
    const float* __restrict__ wq, const float* __restrict__ bq,
    const float* __restrict__ wk, const float* __restrict__ bk,
    float* __restrict__ qloc, float* __restrict__ kloc)
{
    __shared__ float xs[256];
    int bp = blockIdx.x, c = threadIdx.x;
    const float* W  = blockIdx.y ? wk : wq;
    const float* Bv = blockIdx.y ? bk : bq;
    float* dst      = blockIdx.y ? kloc : qloc;
    xs[c] = xloc[bp*256 + c];
    __syncthreads();
    float s = Bv[c];
    #pragma unroll 8
    for (int k = 0; k < 256; ++k)
        s += xs[k] * W[(size_t)k*256 + c];
    dst[bp*256 + c] = s;
}

// ---------------------------------------------------------------- routing top-k (fp32 exact)
__global__ void topk_kern(const float* __restrict__ qloc, const float* __restrict__ kloc,
                          int* __restrict__ Rix)
{
    __shared__ float S[64];
    int b = blockIdx.x, t = threadIdx.x;
    int p = t >> 3, qq = t & 7;
    float s = 0.f;
    for (int c = 0; c < 256; ++c)
        s += qloc[(b*8+p)*256 + c] * kloc[(b*8+qq)*256 + c];
    S[t] = s;
    __syncthreads();
    if (t < 8) {
        float vals[8];
        #pragma unroll
        for (int j = 0; j < 8; ++j) vals[j] = S[t*8 + j];
        for (int j = 0; j < 4; ++j) {
            int best = 0; float bv = vals[0];
            #pragma unroll
            for (int i = 1; i < 8; ++i) if (vals[i] > bv) { bv = vals[i]; best = i; }
            Rix[(b*8 + t)*4 + j] = best;
            vals[best] = -1e30f;
        }
    }
}

// ---------------------------------------------------------------- bf16 MFMA GEMM triple, fp32 A
// First projection triple: A = x (fp32), converted to bf16 during LDS staging (same RNE
// rounding as the old castx pass). Outputs bf16.
__global__ __launch_bounds__(256) void gemm_btx3(
    const float* __restrict__ A,
    const ushort* __restrict__ T0, const ushort* __restrict__ T1, const ushort* __restrict__ T2,
    const float* __restrict__ B0, const float* __restrict__ B1, const float* __restrict__ B2,
    ushort* __restrict__ U0, ushort* __restrict__ U1, ushort* __restrict__ U2)
{
    __shared__ __align__(16) ushort As[32*264];
    int y = blockIdx.y;
    const ushort* T = y==0 ? T0 : (y==1 ? T1 : T2);
    const float* Bi = y==0 ? B0 : (y==1 ? B1 : B2);
    ushort* U = y==0 ? U0 : (y==1 ? U1 : U2);
    int tid = threadIdx.x;
    int m0 = blockIdx.x*32;
    #pragma unroll
    for (int i = 0; i < 4; ++i) {
        int c = i*256 + tid;                 // 1024 chunks of 8
        int pos = c >> 5, off = (c & 31)*8;
        const float* src = A + (size_t)(m0 + pos)*256 + off;
        float4 v0 = *(const float4*)src;
        float4 v1 = *(const float4*)(src + 4);
        ushort4 o0, o1;
        o0.x = f2bf(v0.x); o0.y = f2bf(v0.y); o0.z = f2bf(v0.z); o0.w = f2bf(v0.w);
        o1.x = f2bf(v1.x); o1.y = f2bf(v1.y); o1.z = f2bf(v1.z); o1.w = f2bf(v1.w);
        *(ushort4*)&As[pos*264 + off]     = o0;
        *(ushort4*)&As[pos*264 + off + 4] = o1;
    }
    __syncthreads();
    int w = tid >> 6, lane = tid & 63, lm = lane & 15, lq = lane >> 4;
    const ushort* tb = T + ((size_t)(w*64 + lm))*256 + lq*8;

    f32x4 acc[2][4];
    #pragma unroll
    for (int mt = 0; mt < 2; ++mt)
        #pragma unroll
        for (int nt = 0; nt < 4; ++nt) acc[mt][nt] = (f32x4){0.f,0.f,0.f,0.f};

    bf16x8 bw[4];
    #pragma unroll
    for (int nt = 0; nt < 4; ++nt) bw[nt] = *(const bf16x8*)(tb + nt*4096);

    for (int kc = 0; kc < 8; ++kc) {
        int nk = (kc + 1 < 8) ? kc + 1 : 7;
        bf16x8 bn[4];
        #pragma unroll
        for (int nt = 0; nt < 4; ++nt) bn[nt] = *(const bf16x8*)(tb + nt*4096 + nk*32);
        bf16x8 af[2];
        #pragma unroll
        for (int mt = 0; mt < 2; ++mt)
            af[mt] = *(const bf16x8*)&As[(mt*16 + lm)*264 + kc*32 + lq*8];
        #pragma unroll
        for (int mt = 0; mt < 2; ++mt)
            #pragma unroll
            for (int nt = 0; nt < 4; ++nt)
                acc[mt][nt] = __builtin_amdgcn_mfma_f32_16x16x32_bf16(af[mt], bw[nt], acc[mt][nt], 0,0,0);
        #pragma unroll
        for (int nt = 0; nt < 4; ++nt) bw[nt] = bn[nt];
    }

    #pragma unroll
    for (int mt = 0; mt < 2; ++mt) {
        #pragma unroll
        for (int nt = 0; nt < 4; ++nt) {
            int n = w*64 + nt*16 + lm;
            float bb = Bi[n];
            #pragma unroll
            for (int j = 0; j < 4; ++j) {
                int m = m0 + mt*16 + lq*4 + j;
                U[(size_t)m*256 + n] = f2bf(acc[mt][nt][j] + bb);
            }
        }
    }
}

// ---------------------------------------------------------------- bf16 MFMA GEMM triple, bf16 A
__global__ __launch_bounds__(256) void gemm_bt3(
    const ushort* __restrict__ A0, const ushort* __restrict__ A1, const ushort* __restrict__ A2,
    const ushort* __restrict__ T0, const ushort* __restrict__ T1, const ushort* __restrict__ T2,
    const float* __restrict__ B0, const float* __restrict__ B1, const float* __restrict__ B2,
    ushort* __restrict__ U0, ushort* __restrict__ U1, ushort* __restrict__ U2,
    float* __restrict__ F0, float* __restrict__ F1, float* __restrict__ F2,
    float s0, float s1, float s2)
{
    __shared__ __align__(16) ushort As[32*264];
    int y = blockIdx.y;
    const ushort* A = y==0 ? A0 : (y==1 ? A1 : A2);
    const ushort* T = y==0 ? T0 : (y==1 ? T1 : T2);
    const float* Bi = y==0 ? B0 : (y==1 ? B1 : B2);
    ushort* U = y==0 ? U0 : (y==1 ? U1 : U2);
    float*  F = y==0 ? F0 : (y==1 ? F1 : F2);
    float  sc = y==0 ? s0 : (y==1 ? s1 : s2);
    int tid = threadIdx.x;
    int m0 = blockIdx.x*32;
    #pragma unroll
    for (int i = 0; i < 4; ++i) {
        int c = i*256 + tid;
        int pos = c >> 5, off = (c & 31)*8;
        *(bf16x8*)&As[pos*264 + off] = *(const bf16x8*)(A + (size_t)(m0 + pos)*256 + off);
    }
    __syncthreads();
    int w = tid >> 6, lane = tid & 63, lm = lane & 15, lq = lane >> 4;
    const ushort* tb = T + ((size_t)(w*64 + lm))*256 + lq*8;

    f32x4 acc[2][4];
    #pragma unroll
    for (int mt = 0; mt < 2; ++mt)
        #pragma unroll
        for (int nt = 0; nt < 4; ++nt) acc[mt][nt] = (f32x4){0.f,0.f,0.f,0.f};

    bf16x8 bw[4];
    #pragma unroll
    for (int nt = 0; nt < 4; ++nt) bw[nt] = *(const bf16x8*)(tb + nt*4096);

    for (int kc = 0; kc < 8; ++kc) {
        int nk = (kc + 1 < 8) ? kc + 1 : 7;
        bf16x8 bn[4];
        #pragma unroll
        for (int nt = 0; nt < 4; ++nt) bn[nt] = *(const bf16x8*)(tb + nt*4096 + nk*32);
        bf16x8 af[2];
        #pragma unroll
        for (int mt = 0; mt < 2; ++mt)
            af[mt] = *(const bf16x8*)&As[(mt*16 + lm)*264 + kc*32 + lq*8];
        #pragma unroll
        for (int mt = 0; mt < 2; ++mt)
            #pragma unroll
            for (int nt = 0; nt < 4; ++nt)
                acc[mt][nt] = __builtin_amdgcn_mfma_f32_16x16x32_bf16(af[mt], bw[nt], acc[mt][nt], 0,0,0);
        #pragma unroll
        for (int nt = 0; nt < 4; ++nt) bw[nt] = bn[nt];
    }

    #pragma unroll
    for (int mt = 0; mt < 2; ++mt) {
        #pragma unroll
        for (int nt = 0; nt < 4; ++nt) {
            int n = w*64 + nt*16 + lm;
            float bb = Bi[n];
            #pragma unroll
            for (int j = 0; j < 4; ++j) {
                int m = m0 + mt*16 + lq*4 + j;
                float val = (acc[mt][nt][j] + bb) * sc;
                if (F) F[(size_t)m*256 + n] = val;
                else   U[(size_t)m*256 + n] = f2bf(val);
            }
        }
    }
}

// ---------------------------------------------------------------- V transpose per (bp,h)
__global__ __launch_bounds__(256) void vtrans(
    const ushort* __restrict__ vab, ushort* __restrict__ vt)
{
    __shared__ ushort L[192*36];
    int bph = blockIdx.x;
    int bp = bph >> 3, h = bph & 7;
    int t = threadIdx.x;
    #pragma unroll
    for (int i = 0; i < 6; ++i) {
        int idx = i*256 + t;
        int pos = idx >> 3, c4 = (idx & 7)*4;
        ushort4 v = *(const ushort4*)(vab + ((size_t)(bp*192 + pos))*256 + h*32 + c4);
        *(ushort4*)(L + pos*36 + c4) = v;
    }
    __syncthreads();
    int dk = t >> 3, seg = t & 7;
    size_t ob = ((size_t)bph*32 + dk)*192 + seg*24;
    #pragma unroll
    for (int j = 0; j < 6; ++j) {
        int p0 = seg*24 + j*4;
        ushort4 o;
        o.x = L[(p0+0)*36 + dk];
        o.y = L[(p0+1)*36 + dk];
        o.z = L[(p0+2)*36 + dk];
        o.w = L[(p0+3)*36 + dk];
        *(ushort4*)(vt + ob + j*4) = o;
    }
}

// ---------------------------------------------------------------- MFMA flash attention
__global__ __launch_bounds__(256) void attn_mfma(
    const ushort* __restrict__ qab, const ushort* __restrict__ kab,
    const ushort* __restrict__ vt, const int* __restrict__ Rix,
    float* __restrict__ pl, float* __restrict__ pacc)
{
    __shared__ ushort P[4][16*40];
    int tid = threadIdx.x, w = tid >> 6, lane = tid & 63;
    int lm = lane & 15, lq = lane >> 4;
    int bph = blockIdx.x, kvb = blockIdx.y;
    int bp = bph >> 3, h = bph & 7, b = bp >> 3;
    int r = Rix[bp*4 + kvb];

    bf16x8 qf[3];
    #pragma unroll
    for (int t = 0; t < 3; ++t)
        qf[t] = *(const bf16x8*)(qab + ((size_t)(bp*192 + w*48 + t*16 + lm))*256 + h*32 + lq*8);

    const ushort* kbase = kab + ((size_t)((b*8 + r)*192))*256 + h*32 + lq*8;
    const ushort* vbase = vt + ((size_t)((b*8 + r)*8 + h))*32*192 + lq*8;
    ushort* pw = P[w];

    f32x4 O[3][2];
    #pragma unroll
    for (int t = 0; t < 3; ++t) { O[t][0] = (f32x4){0,0,0,0}; O[t][1] = (f32x4){0,0,0,0}; }
    float l[3] = {0.f, 0.f, 0.f};

    for (int k0 = 0; k0 < 192; k0 += 32) {
        bf16x8 kf0 = *(const bf16x8*)(kbase + (size_t)(k0 + lm)*256);
        bf16x8 kf1 = *(const bf16x8*)(kbase + (size_t)(k0 + 16 + lm)*256);
        bf16x8 vf0 = *(const bf16x8*)(vbase + (size_t)(lm)*192 + k0);
        bf16x8 vf1 = *(const bf16x8*)(vbase + (size_t)(16 + lm)*192 + k0);
        #pragma unroll
        for (int t = 0; t < 3; ++t) {
            f32x4 s0 = __builtin_amdgcn_mfma_f32_16x16x32_bf16(kf0, qf[t], (f32x4){0,0,0,0}, 0,0,0);
            f32x4 s1 = __builtin_amdgcn_mfma_f32_16x16x32_bf16(kf1, qf[t], (f32x4){0,0,0,0}, 0,0,0);
            float p0[4], p1[4];
            #pragma unroll
            for (int j = 0; j < 4; ++j) { p0[j] = __expf(s0[j]); p1[j] = __expf(s1[j]); }
            l[t] += p0[0]+p0[1]+p0[2]+p0[3] + p1[0]+p1[1]+p1[2]+p1[3];
            ushort4 a, c;
            a.x = f2bf(p0[0]); a.y = f2bf(p0[1]); a.z = f2bf(p0[2]); a.w = f2bf(p0[3]);
            c.x = f2bf(p1[0]); c.y = f2bf(p1[1]); c.z = f2bf(p1[2]); c.w = f2bf(p1[3]);
            *(ushort4*)(pw + lm*40 + lq*4)      = a;
            *(ushort4*)(pw + lm*40 + 16 + lq*4) = c;
            bf16x8 pf = *(const bf16x8*)(pw + lm*40 + lq*8);
            O[t][0] = __builtin_amdgcn_mfma_f32_16x16x32_bf16(pf, vf0, O[t][0], 0,0,0);
            O[t][1] = __builtin_amdgcn_mfma_f32_16x16x32_bf16(pf, vf1, O[t][1], 0,0,0);
        }
    }

    #pragma unroll
    for (int t = 0; t < 3; ++t) {
        float lt = l[t];
        lt += __shfl_xor(lt, 16);
        lt += __shfl_xor(lt, 32);
        size_t pbase = ((size_t)(bph*4 + kvb))*192 + w*48 + t*16;
        if (lq == 0) pl[pbase + lm] = lt;
        #pragma unroll
        for (int nt = 0; nt < 2; ++nt)
            #pragma unroll
            for (int reg = 0; reg < 4; ++reg)
                pacc[(pbase + lq*4 + reg)*32 + nt*16 + lm] = O[t][nt][reg];
    }
}

// ---------------------------------------------------------------- merge kv-partials -> ctx bf16
__global__ __launch_bounds__(256) void attn_merge2(
    const float* __restrict__ pl, const float* __restrict__ pacc, ushort* __restrict__ ctxb)
{
    int idx = blockIdx.x*256 + threadIdx.x;
    int d  = idx & 31;
    int gq = idx >> 5;
    int bph = gq / 192;
    int q = gq - bph*192;
    int bp = bph >> 3, h = bph & 7;
    float ls = 0.f, cv = 0.f;
    #pragma unroll
    for (int k = 0; k < 4; ++k) {
        size_t p = ((size_t)(bph*4 + k))*192 + q;
        ls += pl[p];
        cv += pacc[p*32 + d];
    }
    ctxb[((size_t)(bp*192 + q))*256 + h*32 + d] = f2bf(cv / ls);
}

// ---------------------------------------------------------------- padded bf16 conv input (bf16 in)
__global__ __launch_bounds__(256) void addkv_pad2(
    const ushort* __restrict__ kpb, const ushort* __restrict__ vpb, ushort* __restrict__ kvb)
{
    int t  = blockIdx.x*256 + threadIdx.x;
    int ci = (t & 63) * 4;
    int p  = t >> 6;
    int xp = p % 28;
    int rr = p / 28;
    int yp = rr % 68;
    int b  = rr / 68;
    int y = yp - 2, x = xp - 2;
    ushort4 o; o.x = 0; o.y = 0; o.z = 0; o.w = 0;
    if (y >= 0 && y < 64 && x >= 0 && x < 24) {
        size_t base = ((size_t)((b*64 + y)*24 + x))*256 + ci;
        ushort4 a = *(const ushort4*)(kpb + base);
        ushort4 c = *(const ushort4*)(vpb + base);
        o.x = f2bf(bf2f(a.x) + bf2f(c.x));
        o.y = f2bf(bf2f(a.y) + bf2f(c.y));
        o.z = f2bf(bf2f(a.z) + bf2f(c.z));
        o.w = f2bf(bf2f(a.w) + bf2f(c.w));
    }
    *(ushort4*)(kvb + (size_t)p*256 + ci) = o;
}

// ---------------------------------------------------------------- implicit-GEMM conv v4
// v3 + (a) depth-2 register prefetch on B (covers ~2 MFMA-blocks of latency),
// (b) NON-TEMPORAL pconv stores so the 15 MB output stream does not evict the
// 3.3 MB weight tensor from per-XCD L2 (round-6 FETCH_SIZE showed wct HBM re-fetch).
__global__ __launch_bounds__(256) void conv_mfma3(
    const ushort* __restrict__ kvb, const ushort* __restrict__ wct,
    float* __restrict__ pconv)
{
    __shared__ __align__(16) ushort Arows[2][9504];  // 36 pos x 264 (28 real + 8 overrun)
    int tid = threadIdx.x;
    int bid = blockIdx.x;                 // rp*5 + dy
    int rp = bid / 5, dy = bid - rp*5;
    int b = rp >> 5, y0 = (rp & 31)*2;

    const ushort* src0 = kvb + ((size_t)((b*68 + y0 + dy)*28))*256;
    const ushort* src1 = kvb + ((size_t)((b*68 + y0 + 1 + dy)*28))*256;
    #pragma unroll
    for (int i = 0; i < 7; ++i) {
        int c = i*256 + tid;              // 1792 chunks of 8
        int row = (c >= 896);
        int cc = c - row*896;
        int pos = cc >> 5, off = (cc & 31)*8;
        *(bf16x8*)(&Arows[row][pos*264 + off]) =
            *(const bf16x8*)((row ? src1 : src0) + (size_t)(pos*256 + off));
    }
    __syncthreads();

    int w = tid >> 6;
    int lane = tid & 63, lm = lane & 15, lq = lane >> 4;
    const ushort* bbase = wct + ((size_t)((dy*5)*256 + w*64 + lm))*256 + lq*8;
    const ushort* a00 = &Arows[0][lm*264 + lq*8];

    f32x4 acc[2][2][4];
    #pragma unroll
    for (int r = 0; r < 2; ++r)
        #pragma unroll
        for (int mt = 0; mt < 2; ++mt)
            #pragma unroll
            for (int nt = 0; nt < 4; ++nt)
                acc[r][mt][nt] = (f32x4){0.f,0.f,0.f,0.f};

    // depth-2 rolling B prefetch: b0 = iter, b1 = iter+1, bn = iter+2
    bf16x8 b0[4], b1[4];
    #pragma unroll
    for (int nt = 0; nt < 4; ++nt) b0[nt] = *(const bf16x8*)(bbase + nt*4096);
    #pragma unroll
    for (int nt = 0; nt < 4; ++nt) b1[nt] = *(const bf16x8*)(bbase + 32 + nt*4096);

    for (int iter = 0; iter < 40; ++iter) {          // iter = dx*8 + ch
        int i2 = (iter + 2 < 40) ? iter + 2 : 39;
        int boff = (i2 >> 3)*65536 + (i2 & 7)*32;
        bf16x8 bn[4];
        #pragma unroll
        for (int nt = 0; nt < 4; ++nt) bn[nt] = *(const bf16x8*)(bbase + boff + nt*4096);

        int aoff = (iter >> 3)*264 + (iter & 7)*32;  // dx*264 + ch*32
        bf16x8 af[2][2];
        #pragma unroll
        for (int r = 0; r < 2; ++r)
            #pragma unroll
            for (int mt = 0; mt < 2; ++mt)
                af[r][mt] = *(const bf16x8*)(a00 + r*9504 + mt*4224 + aoff);

        #pragma unroll
        for (int r = 0; r < 2; ++r)
            #pragma unroll
            for (int mt = 0; mt < 2; ++mt)
                #pragma unroll
                for (int nt = 0; nt < 4; ++nt)
                    acc[r][mt][nt] = __builtin_amdgcn_mfma_f32_16x16x32_bf16(
                        af[r][mt], b0[nt], acc[r][mt][nt], 0, 0, 0);

        #pragma unroll
        for (int nt = 0; nt < 4; ++nt) { b0[nt] = b1[nt]; b1[nt] = bn[nt]; }
    }

    #pragma unroll
    for (int r = 0; r < 2; ++r) {
        int grow = rp*2 + r;
        #pragma unroll
        for (int mt = 0; mt < 2; ++mt) {
            #pragma unroll
            for (int nt = 0; nt < 4; ++nt) {
                #pragma unroll
                for (int j = 0; j < 4; ++j) {
                    int x = mt*16 + lq*4 + j;
                    if (x < 24)
                        __builtin_nontemporal_store(acc[r][mt][nt][j],
                            &pconv[((size_t)(dy*3072 + grow*24 + x))*256 + w*64 + nt*16 + lm]);
                }
            }
        }
    }
}

// ---------------------------------------------------------------- LN1: x + routing
__global__ __launch_bounds__(256) void ln_add(
    const float* __restrict__ A, const float* __restrict__ B1,
    const float* __restrict__ gamma, const float* __restrict__ beta,
    float* __restrict__ out)
{
    int pos  = blockIdx.x*4 + (threadIdx.x >> 6);
    int lane = threadIdx.x & 63;
    size_t base = (size_t)pos*256 + lane*4;
    float4 a = *(const float4*)(A + base);
    float4 b = *(const float4*)(B1 + base);
    float x0 = a.x + b.x, x1 = a.y + b.y, x2 = a.z + b.z, x3 = a.w + b.w;
    float s  = x0 + x1 + x2 + x3;
    float sq = x0*x0 + x1*x1 + x2*x2 + x3*x3;
    #pragma unroll
    for (int off = 32; off > 0; off >>= 1) {
        s  += __shfl_xor(s,  off);
        sq += __shfl_xor(sq, off);
    }
    float mean = s * (1.0f/256.0f);
    float var  = sq * (1.0f/256.0f) - mean*mean;
    float rstd = rsqrtf(var + 1e-5f);
    float4 gv = *(const float4*)(gamma + lane*4);
    float4 bv = *(const float4*)(beta  + lane*4);
    float4 o;
    o.x = (x0 - mean)*rstd*gv.x + bv.x;
    o.y = (x1 - mean)*rstd*gv.y + bv.y;
    o.z = (x2 - mean)*rstd*gv.z + bv.z;
    o.w = (x3 - mean)*rstd*gv.w + bv.w;
    *(float4*)(out + base) = o;
}

// ---------------------------------------------------------------- LN2 fused with dy-reduce
// out = LN(x_res + (bias + sum_dy pconv)); identical add order to reduce5+ln_add.
__global__ __launch_bounds__(256) void ln2_fused(
    const float* __restrict__ xr, const float* __restrict__ pc, const float* __restrict__ cb,
    const float* __restrict__ gamma, const float* __restrict__ beta,
    float* __restrict__ out)
{
    int pos  = blockIdx.x*4 + (threadIdx.x >> 6);
    int lane = threadIdx.x & 63;
    size_t base = (size_t)pos*256 + lane*4;
    float4 gsum = *(const float4*)(cb + lane*4);
    #pragma unroll
    for (int d = 0; d < 5; ++d) {
        float4 v = *(const float4*)(pc + (size_t)d*NE + base);
        gsum.x += v.x; gsum.y += v.y; gsum.z += v.z; gsum.w += v.w;
    }
    float4 a = *(const float4*)(xr + base);
    float x0 = a.x + gsum.x, x1 = a.y + gsum.y, x2 = a.z + gsum.z, x3 = a.w + gsum.w;
    float s  = x0 + x1 + x2 + x3;
    float sq = x0*x0 + x1*x1 + x2*x2 + x3*x3;
    #pragma unroll
    for (int off = 32; off > 0; off >>= 1) {
        s  += __shfl_xor(s,  off);
        sq += __shfl_xor(sq, off);
    }
    float mean = s * (1.0f/256.0f);
    float var  = sq * (1.0f/256.0f) - mean*mean;
    float rstd = rsqrtf(var + 1e-5f);
    float4 gv = *(const float4*)(gamma + lane*4);
    float4 bv = *(const float4*)(beta  + lane*4);
    float4 o;
    o.x = (x0 - mean)*rstd*gv.x + bv.x;
    o.y = (x1 - mean)*rstd*gv.y + bv.y;
    o.z = (x2 - mean)*rstd*gv.z + bv.z;
    o.w = (x3 - mean)*rstd*gv.w + bv.w;
    *(float4*)(out + base) = o;
}

// ---------------------------------------------------------------- launcher
extern "C" void kernel_launch(void* const* d_in, const int* in_sizes, int n_in,
                              void* d_out, int out_size, void* d_ws, size_t ws_size,
                              hipStream_t stream)
{
    (void)in_sizes; (void)n_in; (void)out_size; (void)ws_size;
    const float* x    = (const float*)d_in[0];
    const float* wq   = (const float*)d_in[1];
    const float* bq   = (const float*)d_in[2];
    const float* wk   = (const float*)d_in[3];
    const float* bk   = (const float*)d_in[4];
    const float* wv   = (const float*)d_in[5];
    const float* bv   = (const float*)d_in[6];
    const float* wqa  = (const float*)d_in[7];
    const float* bqa  = (const float*)d_in[8];
    const float* wka  = (const float*)d_in[9];
    const float* bka  = (const float*)d_in[10];
    const float* wva  = (const float*)d_in[11];
    const float* bva  = (const float*)d_in[12];
    const float* woa  = (const float*)d_in[13];
    const float* boa  = (const float*)d_in[14];
    const float* cw   = (const float*)d_in[15];
    const float* cbi  = (const float*)d_in[16];
    const float* ln1g = (const float*)d_in[17];
    const float* ln1b = (const float*)d_in[18];
    const float* ln2g = (const float*)d_in[19];
    const float* ln2b = (const float*)d_in[20];
    float* out = (float*)d_out;

    float* ws = (float*)d_ws;
    const size_t HNE = NE/2;
    ushort* qpb = (ushort*)(ws + 0*HNE);
    ushort* kpb = (ushort*)(ws + 1*HNE);
    ushort* xb  = (ushort*)(ws + 2*HNE);   // slot only used as x_res (fp32) now
    ushort* vpb = (ushort*)(ws + 3*HNE);
    ushort* qab = (ushort*)(ws + 4*HNE);
    ushort* kab = (ushort*)(ws + 5*HNE);
    ushort* vab = (ushort*)(ws + 6*HNE);
    ushort* vt  = (ushort*)(ws + 7*HNE);
    float* R    = ws + 8*HNE;              // 3,932,160 floats
    float* pacc = R;
    float* pl   = R + 3145728;
    float* pconv= R;
    ushort* wt7 = (ushort*)(R + 3932160);
    ushort* wct = (ushort*)(R + 3932160 + 229376);
    ushort* kvb = (ushort*)(R + 3932160 + 229376 + 819200);
    float* xloc = R + 3932160 + 229376 + 819200 + 487424;
    float* qloc = xloc + 4096;
    float* kloc = qloc + 4096;
    int*   Rix  = (int*)(kloc + 4096);
    // fp32 aliases over dead bf16 slots:
    float* routing = (float*)qpb;   // qpb+kpb dead after gemm2/addkv
    float* x_res   = (float*)xb;    // xb slot free; vpb dead after gemm2/addkv
    ushort* ctxb   = vab;           // vab dead after vtrans

    // 1. weight preps
    wtrans7<<<dim3(16,7), 256, 0, stream>>>(wq,wk,wv,wqa,wka,wva,woa, wt7);
    wtrans<<<400, 256, 0, stream>>>(cw, wct);
    // 2. routing descriptors in exact fp32 (mean commutes with projection)
    xmean<<<16, 256, 0, stream>>>(x, xloc);
    qkloc_kern<<<dim3(16,2), 256, 0, stream>>>(xloc, wq,bq, wk,bk, qloc, kloc);
    topk_kern<<<2, 64, 0, stream>>>(qloc, kloc, Rix);
    // 3. q/k/v projections (bf16 MFMA, fp32 A staged+converted in-kernel)
    gemm_btx3<<<dim3(96,3), 256, 0, stream>>>(
        x, wt7, wt7+65536, wt7+131072, bq,bk,bv, qpb,kpb,vpb);
    // 4. conv input (bf16)
    addkv_pad2<<<952, 256, 0, stream>>>(kpb, vpb, kvb);
    // 5. attention projections (qab pre-scaled by 1/sqrt(dk))
    gemm_bt3<<<dim3(96,3), 256, 0, stream>>>(
        qpb,kpb,vpb, wt7+196608, wt7+262144, wt7+327680, bqa,bka,bva,
        qab,kab,vab, nullptr,nullptr,nullptr, 0.17677669529663687f,1.f,1.f);
    // 6. V transpose, 7. MFMA flash attention, 8. merge -> ctx bf16
    vtrans<<<128, 256, 0, stream>>>(vab, vt);
    attn_mfma<<<dim3(128,4), 256, 0, stream>>>(qab, kab, vt, Rix, pl, pacc);
    attn_merge2<<<NE/256, 256, 0, stream>>>(pl, pacc, ctxb);
    // 9. output projection (bf16 MFMA -> fp32)
    gemm_bt3<<<dim3(96,1), 256, 0, stream>>>(
        ctxb,ctxb,ctxb, wt7+393216, wt7+393216, wt7+393216, boa,boa,boa,
        nullptr,nullptr,nullptr, routing,routing,routing, 1.f,1.f,1.f);
    // 10. LN1(x + routing)
    ln_add<<<NPOS/4, 256, 0, stream>>>(x, routing, ln1g, ln1b, x_res);
    // 11. conv v4 (nt stores keep wct L2-resident; depth-2 B prefetch)
    conv_mfma3<<<320, 256, 0, stream>>>(kvb, wct, pconv);
    // 12. LN2 fused with dy-reduce + bias -> out
    ln2_fused<<<NPOS/4, 256, 0, stream>>>(x_res, pconv, cbi, ln2g, ln2b, out);
}